// Round 2
// baseline (377.428 us; speedup 1.0000x reference)
//
#include <hip/hip_runtime.h>
#include <math.h>

#define HW 65536
#define NPX 524288      // 8*256*256
#define NEL 1572864     // 8*3*256*256

// ---- ws layout (float offsets) ----
#define ACC_OFF   0      // scalars: 0 l1,1 sL,2 sab,3 S2,4 S4,5 d1,6 d2,7 wnum,8 wsat,9 wm
#define CURVE_CNT 16     // 96
#define CURVE_PS  112    // 96
#define CURVE_TS  208    // 96
#define HIST_OFF  304    // 48*64 = 3072 -> ends at 3376
#define ZERO_FLOATS 3376
// mask/blur scratch (used first, then overwritten by FFT buffers)
#define MASK_OFF  4096
#define TMP_OFF   (4096 + 524288)
// FFT buffers OVERLAP mask/tmp (stream ordering: mask pipeline done first)
#define FFT_P     4096                      // 24 slices * 66048 floats
#define FFT_T     (FFT_P + 24*66048)
// total floats = FFT_T + 24*66048 = 3,174,400  (~12.7 MB)

// ---------- helpers ----------
__device__ __forceinline__ float labF(float t) {
    return t > 0.008856452f ? cbrtf(t) : t * 7.787037f + 0.13793103f;
}

__device__ __forceinline__ void rgb2lab(float r, float g, float b,
                                        float& L, float& A, float& Bc) {
    float lr = r > 0.04045f ? powf((r + 0.055f) * (1.0f/1.055f), 2.4f) : r * (1.0f/12.92f);
    float lg = g > 0.04045f ? powf((g + 0.055f) * (1.0f/1.055f), 2.4f) : g * (1.0f/12.92f);
    float lb = b > 0.04045f ? powf((b + 0.055f) * (1.0f/1.055f), 2.4f) : b * (1.0f/12.92f);
    float X = (0.4124564f*lr + 0.3575761f*lg + 0.1804375f*lb) * (1.0f/0.95047f);
    float Y = (0.2126729f*lr + 0.7151522f*lg + 0.0721750f*lb);
    float Z = (0.0193339f*lr + 0.1191920f*lg + 0.9503041f*lb) * (1.0f/1.08883f);
    float fx = labF(X), fy = labF(Y), fz = labF(Z);
    L = 116.f*fy - 16.f;
    A = 500.f*(fx - fy);
    Bc = 200.f*(fy - fz);
}

// block-wide sum; returns total on thread 0 (0 elsewhere); ends with barrier
__device__ __forceinline__ float blockSum(float v, float* sb) {
    #pragma unroll
    for (int o = 32; o > 0; o >>= 1) v += __shfl_down(v, o, 64);
    int lane = threadIdx.x & 63, w = threadIdx.x >> 6;
    if (lane == 0) sb[w] = v;
    __syncthreads();
    float r = 0.f;
    if (threadIdx.x == 0) {
        int nw = (blockDim.x + 63) >> 6;
        for (int i = 0; i < nw; ++i) r += sb[i];
    }
    __syncthreads();
    return r;
}

// ---------- K1: pointwise (L1, LAB, target mask) ----------
__global__ void k_point(const float* __restrict__ pred, const float* __restrict__ targ,
                        float* __restrict__ ws) {
    int i = blockIdx.x * blockDim.x + threadIdx.x;   // < NPX
    int b = i >> 16, hw = i & 65535;
    const float* p = pred + b*3*HW + hw;
    const float* t = targ + b*3*HW + hw;
    float pr = p[0], pg = p[HW], pb = p[2*HW];
    float tr = t[0], tg = t[HW], tb = t[2*HW];
    float e3 = fabsf(pr-tr) + fabsf(pg-tg) + fabsf(pb-tb);
    float Lp,Ap,Bp, Lt,At,Bt;
    rgb2lab(pr,pg,pb, Lp,Ap,Bp);
    rgb2lab(tr,tg,tb, Lt,At,Bt);
    float sL = fabsf(Lp-Lt);
    float sab = fabsf(Ap-At) + fabsf(Bp-Bt);
    float tmx = fmaxf(tr, fmaxf(tg, tb)), tmn = fminf(tr, fminf(tg, tb));
    float tsat = (tmx - tmn + 1e-7f) / (tmx + 1e-7f);
    ws[MASK_OFF + i] = (tmx > 0.6f && tsat > 0.2f) ? 1.f : 0.f;
    __shared__ float sb[8];
    float v;
    v = blockSum(e3, sb);  if (threadIdx.x == 0) atomicAdd(&ws[0], v);
    v = blockSum(sL, sb);  if (threadIdx.x == 0) atomicAdd(&ws[1], v);
    v = blockSum(sab, sb); if (threadIdx.x == 0) atomicAdd(&ws[2], v);
}

// ---------- K2: multi-scale pooled L1 ----------
__global__ void k_ms(const float* __restrict__ pred, const float* __restrict__ targ,
                     float* __restrict__ ws) {
    int t = blockIdx.x * blockDim.x + threadIdx.x;   // < 98304
    int sc = t >> 12;              // (b,c) slice 0..23
    int q = t & 4095;
    int y4 = q >> 6, x4 = q & 63;
    const float* pp = pred + sc*HW + (y4*4)*256 + x4*4;
    const float* tp = targ + sc*HW + (y4*4)*256 + x4*4;
    float4 p0 = *(const float4*)(pp);
    float4 p1 = *(const float4*)(pp + 256);
    float4 p2 = *(const float4*)(pp + 512);
    float4 p3 = *(const float4*)(pp + 768);
    float4 q0 = *(const float4*)(tp);
    float4 q1 = *(const float4*)(tp + 256);
    float4 q2 = *(const float4*)(tp + 512);
    float4 q3 = *(const float4*)(tp + 768);
    float a00 = (p0.x+p0.y+p1.x+p1.y)*0.25f, a01 = (p0.z+p0.w+p1.z+p1.w)*0.25f;
    float a10 = (p2.x+p2.y+p3.x+p3.y)*0.25f, a11 = (p2.z+p2.w+p3.z+p3.w)*0.25f;
    float b00 = (q0.x+q0.y+q1.x+q1.y)*0.25f, b01 = (q0.z+q0.w+q1.z+q1.w)*0.25f;
    float b10 = (q2.x+q2.y+q3.x+q3.y)*0.25f, b11 = (q2.z+q2.w+q3.z+q3.w)*0.25f;
    float s2 = fabsf(a00-b00)+fabsf(a01-b01)+fabsf(a10-b10)+fabsf(a11-b11);
    float s4 = fabsf((a00+a01+a10+a11)*0.25f - (b00+b01+b10+b11)*0.25f);
    __shared__ float sb[8];
    float v;
    v = blockSum(s2, sb); if (threadIdx.x == 0) atomicAdd(&ws[3], v);
    v = blockSum(s4, sb); if (threadIdx.x == 0) atomicAdd(&ws[4], v);
}

// ---------- K3: color-curve segment sums ----------
__global__ void k_curve(const float* __restrict__ pred, const float* __restrict__ targ,
                        const float* __restrict__ inp, float* __restrict__ ws) {
    __shared__ float c[96], s1[96], s2[96];
    for (int j = threadIdx.x; j < 96; j += blockDim.x) { c[j]=0.f; s1[j]=0.f; s2[j]=0.f; }
    __syncthreads();
    for (int e = blockIdx.x*blockDim.x + threadIdx.x; e < NEL; e += gridDim.x*blockDim.x) {
        int ch = (e >> 16) % 3;
        int idx = (int)(inp[e] * 32.f);
        idx = min(max(idx, 0), 31);
        int seg = idx + 32*ch;
        atomicAdd(&c[seg], 1.f);
        atomicAdd(&s1[seg], pred[e]);
        atomicAdd(&s2[seg], targ[e]);
    }
    __syncthreads();
    for (int j = threadIdx.x; j < 96; j += blockDim.x) {
        atomicAdd(&ws[CURVE_CNT+j], c[j]);
        atomicAdd(&ws[CURVE_PS+j], s1[j]);
        atomicAdd(&ws[CURVE_TS+j], s2[j]);
    }
}

// ---------- K4: soft histogram (thread-owns-bin) ----------
__global__ void k_hist(const float* __restrict__ pred, const float* __restrict__ targ,
                       float* __restrict__ ws) {
    int blk = blockIdx.x;          // 48*16
    int s = blk >> 4, part = blk & 15;
    const float* src = (s < 24 ? pred + s*HW : targ + (s-24)*HW) + part*4096;
    int bin = threadIdx.x & 63, qd = threadIdx.x >> 6;
    float cb = (float)bin * (1.f/63.f);
    float acc = 0.f;
    __shared__ float st[256];
    for (int tile = 0; tile < 16; ++tile) {
        __syncthreads();
        st[threadIdx.x] = src[tile*256 + threadIdx.x];
        __syncthreads();
        const float* xs = st + qd*64;
        #pragma unroll
        for (int j = 0; j < 64; ++j) {
            float d = xs[j] - cb;
            acc += __expf(-d*d*2048.f);   // 1/(2*bw^2), bw = 1/64
        }
    }
    __syncthreads();
    st[threadIdx.x] = acc;
    __syncthreads();
    if (threadIdx.x < 64) {
        float tot = st[threadIdx.x] + st[threadIdx.x+64] + st[threadIdx.x+128] + st[threadIdx.x+192];
        atomicAdd(&ws[HIST_OFF + s*64 + threadIdx.x], tot);
    }
}

// ---------- K5: horizontal 11-tap box sum on mask ----------
__global__ void k_blurh(float* __restrict__ ws) {
    int i = blockIdx.x*blockDim.x + threadIdx.x;  // NPX
    int x = i & 255;
    const float* m = ws + MASK_OFF;
    float s = 0.f;
    #pragma unroll
    for (int d = -5; d <= 5; ++d) {
        int xx = x + d;
        if (xx >= 0 && xx < 256) s += m[i - x + xx];
    }
    ws[TMP_OFF + i] = s;
}

// ---------- K6: vertical blur + window-boost accumulation ----------
__global__ void k_win(const float* __restrict__ pred, const float* __restrict__ targ,
                      float* __restrict__ ws) {
    int i = blockIdx.x*blockDim.x + threadIdx.x;
    int b = i >> 16, hw = i & 65535, y = hw >> 8;
    const float* tm = ws + TMP_OFF + b*HW;
    float s = 0.f;
    #pragma unroll
    for (int d = -5; d <= 5; ++d) {
        int yy = y + d;
        if (yy >= 0 && yy < 256) s += tm[hw + d*256];
    }
    float m = s * (1.f/121.f);
    const float* p = pred + b*3*HW + hw;
    const float* t = targ + b*3*HW + hw;
    float pr = p[0], pg = p[HW], pb = p[2*HW];
    float tr = t[0], tg = t[HW], tb = t[2*HW];
    float e3 = fabsf(pr-tr) + fabsf(pg-tg) + fabsf(pb-tb);
    float tmx = fmaxf(tr, fmaxf(tg, tb)), tmn = fminf(tr, fminf(tg, tb));
    float tsat = (tmx - tmn + 1e-7f) / (tmx + 1e-7f);
    float pmx = fmaxf(pr, fmaxf(pg, pb)), pmn = fminf(pr, fminf(pg, pb));
    float psat = (pmx - pmn + 1e-7f) / (pmx + 1e-7f);
    float sd = fabsf(psat - tsat);
    __shared__ float sb[8];
    float v;
    v = blockSum(e3*m, sb); if (threadIdx.x == 0) atomicAdd(&ws[7], v);
    v = blockSum(sd*m, sb); if (threadIdx.x == 0) atomicAdd(&ws[8], v);
    v = blockSum(m,    sb); if (threadIdx.x == 0) atomicAdd(&ws[9], v);
}

// ---------- FFT helpers ----------
// radix-2 DIT on 256 complex in LDS; `l` in 0..63 does butterflies l and l+64
__device__ __forceinline__ void fft256(float2* a, int l) {
    #pragma unroll
    for (int st = 0; st < 8; ++st) {
        int half = 1 << st, m = half << 1;
        #pragma unroll
        for (int k = 0; k < 2; ++k) {
            int bb = l + 64*k;
            int j = bb & (half - 1);
            int i0 = ((bb >> st) << (st + 1)) + j;
            int i1 = i0 + half;
            float ang = -6.283185307f * (float)j / (float)m;
            float si, co;
            __sincosf(ang, &si, &co);
            float2 u = a[i0], v = a[i1];
            float2 w = make_float2(v.x*co - v.y*si, v.x*si + v.y*co);
            a[i0] = make_float2(u.x + w.x, u.y + w.y);
            a[i1] = make_float2(u.x - w.x, u.y - w.y);
        }
        __syncthreads();
    }
}

// ---------- K7: row FFT (real input -> 129 bins) ----------
__global__ __launch_bounds__(64) void k_fft_row(const float* __restrict__ pred,
                                                const float* __restrict__ targ,
                                                float* __restrict__ ws) {
    int bid = blockIdx.x;          // 48*256
    int s = bid >> 8, r = bid & 255;
    const float* src = (s < 24 ? pred + s*HW : targ + (s-24)*HW) + r*256;
    float2* out = (float2*)(ws + (s < 24 ? FFT_P + s*66048 : FFT_T + (s-24)*66048)) + r*129;
    __shared__ float2 a[256];
    int tid = threadIdx.x;
    #pragma unroll
    for (int j = 0; j < 4; ++j) {
        int i = tid + 64*j;
        a[__brev((unsigned)i) >> 24] = make_float2(src[i], 0.f);
    }
    __syncthreads();
    fft256(a, tid);
    out[tid] = a[tid];
    out[tid + 64] = a[tid + 64];
    if (tid == 0) out[128] = a[128];
}

// ---------- K8: column FFT (pred+target) + focal-freq sums ----------
__global__ __launch_bounds__(128) void k_fft_col(float* __restrict__ ws) {
    int bid = blockIdx.x;          // 24*129
    int s = bid / 129, k = bid - s*129;
    __shared__ float2 ap[256], at[256];
    __shared__ float sb[8];
    int tid = threadIdx.x;
    int l = tid & 63, g = tid >> 6;
    float2* arr = g ? at : ap;
    const float2* src = (const float2*)(ws + (g ? FFT_T : FFT_P)) + s*33024 + k;
    #pragma unroll
    for (int j = 0; j < 4; ++j) {
        int r = l + 64*j;
        arr[__brev((unsigned)r) >> 24] = src[r*129];
    }
    __syncthreads();
    fft256(arr, l);
    float d1 = 0.f, d2 = 0.f;
    #pragma unroll
    for (int j = 0; j < 2; ++j) {
        int r = tid + 128*j;
        float2 zp = ap[r], zt = at[r];
        float mp = sqrtf(zp.x*zp.x + zp.y*zp.y);
        float mt = sqrtf(zt.x*zt.x + zt.y*zt.y);
        float d = fabsf(mt - mp) * (1.f/256.f);
        d1 += d; d2 += d*d;
    }
    float v;
    v = blockSum(d1, sb); if (tid == 0) atomicAdd(&ws[5], v);
    v = blockSum(d2, sb); if (tid == 0) atomicAdd(&ws[6], v);
}

// ---------- K9: final assembly ----------
__global__ void k_final(const float* __restrict__ ws, float* __restrict__ out) {
    __shared__ float red[256];
    int tid = threadIdx.x;
    // curve
    float cv = 0.f;
    if (tid < 96) {
        float cnt = ws[CURVE_CNT + tid];
        if (cnt > 0.f) cv = fabsf(ws[CURVE_PS + tid] - ws[CURVE_TS + tid]) / cnt;
    }
    red[tid] = cv;
    __syncthreads();
    for (int o = 128; o > 0; o >>= 1) { if (tid < o) red[tid] += red[tid + o]; __syncthreads(); }
    float curve = red[0] / 96.f;
    __syncthreads();
    // histogram EMD
    float hacc = 0.f;
    if (tid < 24) {
        const float* hp = ws + HIST_OFF + tid*64;
        const float* ht = ws + HIST_OFF + (24 + tid)*64;
        float sp = 0.f, stt = 0.f;
        for (int k = 0; k < 64; ++k) { sp += hp[k]; stt += ht[k]; }
        float ip = 1.f / (sp + 1e-7f), it = 1.f / (stt + 1e-7f);
        float cp = 0.f, ct = 0.f;
        for (int k = 0; k < 64; ++k) {
            cp += hp[k] * ip;
            ct += ht[k] * it;
            hacc += fabsf(cp - ct);
        }
    }
    red[tid] = hacc;
    __syncthreads();
    for (int o = 128; o > 0; o >>= 1) { if (tid < o) red[tid] += red[tid + o]; __syncthreads(); }
    float hl = red[0] / 1536.f;
    if (tid == 0) {
        float l1  = ws[0] / (float)NEL;
        float lab = (ws[1] / (float)NPX) * 0.01f + 2.f * (ws[2] / (2.f * (float)NPX * 128.f));
        float ms  = (l1 + ws[3] / 393216.f + ws[4] / 98304.f) * (1.f/3.f);
        const float M = 792576.f;
        float ff  = (ws[6] / M) / (ws[5] / M + 1e-8f);
        float wm  = ws[9];
        float wb  = ws[7] / (wm*3.f + 1e-7f) + 0.5f * (ws[8] / (wm + 1e-7f));
        out[0] = l1 + 0.3f*ff + 0.4f*lab + 0.3f*ms + 0.4f*curve + 0.2f*hl + 0.5f*wb;
    }
}

extern "C" void kernel_launch(void* const* d_in, const int* in_sizes, int n_in,
                              void* d_out, int out_size, void* d_ws, size_t ws_size,
                              hipStream_t stream) {
    const float* pred = (const float*)d_in[0];
    const float* targ = (const float*)d_in[1];
    const float* inp  = (const float*)d_in[2];
    float* ws = (float*)d_ws;
    float* out = (float*)d_out;

    hipMemsetAsync(d_ws, 0, ZERO_FLOATS * sizeof(float), stream);

    // mask pipeline first (its scratch is overwritten by the FFT buffers)
    k_point  <<<2048, 256, 0, stream>>>(pred, targ, ws);
    k_blurh  <<<2048, 256, 0, stream>>>(ws);
    k_win    <<<2048, 256, 0, stream>>>(pred, targ, ws);
    // independent reductions
    k_ms     <<<384,  256, 0, stream>>>(pred, targ, ws);
    k_curve  <<<768,  256, 0, stream>>>(pred, targ, inp, ws);
    k_hist   <<<768,  256, 0, stream>>>(pred, targ, ws);
    // FFT (reuses mask/tmp scratch region)
    k_fft_row<<<12288, 64, 0, stream>>>(pred, targ, ws);
    k_fft_col<<<3096, 128, 0, stream>>>(ws);
    k_final  <<<1,    256, 0, stream>>>(ws, out);
}

// Round 4
// 281.981 us; speedup vs baseline: 1.3385x; 1.3385x over previous
//
#include <hip/hip_runtime.h>
#include <math.h>

#define HW 65536
#define NPX 524288      // 8*256*256
#define NEL 1572864     // 8*3*256*256

// ---- ws layout (float offsets) ----
#define ACC_OFF   0      // scalars: 0 l1,1 sL,2 sab,3 S2,4 S4,5 d1,6 d2,7 wnum,8 wsat,9 wm
#define CURVE_CNT 16     // 96
#define CURVE_PS  112    // 96
#define CURVE_TS  208    // 96
#define HIST_OFF  304    // 48*64 = 3072 -> ends at 3376
#define ZERO_FLOATS 3376
// mask/blur scratch (used first, then overwritten by FFT buffers)
#define MASK_OFF  4096
#define TMP_OFF   (4096 + 524288)
// FFT buffers OVERLAP mask/tmp (stream ordering: mask pipeline done first)
#define FFT_P     4096                      // 24 slices * 66048 floats
#define FFT_T     (FFT_P + 24*66048)
// total floats = FFT_T + 24*66048 = 3,174,400  (~12.7 MB)

#define CURVE_SCALE 131072.0f     // 2^17 fixed-point; 8192 elems/block * 2^17 = 2^30 < u32 max

// ---------- helpers ----------
__device__ __forceinline__ float labF(float t) {
    return t > 0.008856452f ? cbrtf(t) : t * 7.787037f + 0.13793103f;
}

__device__ __forceinline__ void rgb2lab(float r, float g, float b,
                                        float& L, float& A, float& Bc) {
    float lr = r > 0.04045f ? powf((r + 0.055f) * (1.0f/1.055f), 2.4f) : r * (1.0f/12.92f);
    float lg = g > 0.04045f ? powf((g + 0.055f) * (1.0f/1.055f), 2.4f) : g * (1.0f/12.92f);
    float lb = b > 0.04045f ? powf((b + 0.055f) * (1.0f/1.055f), 2.4f) : b * (1.0f/12.92f);
    float X = (0.4124564f*lr + 0.3575761f*lg + 0.1804375f*lb) * (1.0f/0.95047f);
    float Y = (0.2126729f*lr + 0.7151522f*lg + 0.0721750f*lb);
    float Z = (0.0193339f*lr + 0.1191920f*lg + 0.9503041f*lb) * (1.0f/1.08883f);
    float fx = labF(X), fy = labF(Y), fz = labF(Z);
    L = 116.f*fy - 16.f;
    A = 500.f*(fx - fy);
    Bc = 200.f*(fy - fz);
}

// block-wide sum; returns total on thread 0 (0 elsewhere); ends with barrier
__device__ __forceinline__ float blockSum(float v, float* sb) {
    #pragma unroll
    for (int o = 32; o > 0; o >>= 1) v += __shfl_down(v, o, 64);
    int lane = threadIdx.x & 63, w = threadIdx.x >> 6;
    if (lane == 0) sb[w] = v;
    __syncthreads();
    float r = 0.f;
    if (threadIdx.x == 0) {
        int nw = (blockDim.x + 63) >> 6;
        for (int i = 0; i < nw; ++i) r += sb[i];
    }
    __syncthreads();
    return r;
}

// ---------- K1: pointwise (L1, LAB, target mask) ----------
__global__ void k_point(const float* __restrict__ pred, const float* __restrict__ targ,
                        float* __restrict__ ws) {
    int i = blockIdx.x * blockDim.x + threadIdx.x;   // < NPX
    int b = i >> 16, hw = i & 65535;
    const float* p = pred + b*3*HW + hw;
    const float* t = targ + b*3*HW + hw;
    float pr = p[0], pg = p[HW], pb = p[2*HW];
    float tr = t[0], tg = t[HW], tb = t[2*HW];
    float e3 = fabsf(pr-tr) + fabsf(pg-tg) + fabsf(pb-tb);
    float Lp,Ap,Bp, Lt,At,Bt;
    rgb2lab(pr,pg,pb, Lp,Ap,Bp);
    rgb2lab(tr,tg,tb, Lt,At,Bt);
    float sL = fabsf(Lp-Lt);
    float sab = fabsf(Ap-At) + fabsf(Bp-Bt);
    float tmx = fmaxf(tr, fmaxf(tg, tb)), tmn = fminf(tr, fminf(tg, tb));
    float tsat = (tmx - tmn + 1e-7f) / (tmx + 1e-7f);
    ws[MASK_OFF + i] = (tmx > 0.6f && tsat > 0.2f) ? 1.f : 0.f;
    __shared__ float sb[8];
    float v;
    v = blockSum(e3, sb);  if (threadIdx.x == 0) atomicAdd(&ws[0], v);
    v = blockSum(sL, sb);  if (threadIdx.x == 0) atomicAdd(&ws[1], v);
    v = blockSum(sab, sb); if (threadIdx.x == 0) atomicAdd(&ws[2], v);
}

// ---------- K2: multi-scale pooled L1 ----------
__global__ void k_ms(const float* __restrict__ pred, const float* __restrict__ targ,
                     float* __restrict__ ws) {
    int t = blockIdx.x * blockDim.x + threadIdx.x;   // < 98304
    int sc = t >> 12;              // (b,c) slice 0..23
    int q = t & 4095;
    int y4 = q >> 6, x4 = q & 63;
    const float* pp = pred + sc*HW + (y4*4)*256 + x4*4;
    const float* tp = targ + sc*HW + (y4*4)*256 + x4*4;
    float4 p0 = *(const float4*)(pp);
    float4 p1 = *(const float4*)(pp + 256);
    float4 p2 = *(const float4*)(pp + 512);
    float4 p3 = *(const float4*)(pp + 768);
    float4 q0 = *(const float4*)(tp);
    float4 q1 = *(const float4*)(tp + 256);
    float4 q2 = *(const float4*)(tp + 512);
    float4 q3 = *(const float4*)(tp + 768);
    float a00 = (p0.x+p0.y+p1.x+p1.y)*0.25f, a01 = (p0.z+p0.w+p1.z+p1.w)*0.25f;
    float a10 = (p2.x+p2.y+p3.x+p3.y)*0.25f, a11 = (p2.z+p2.w+p3.z+p3.w)*0.25f;
    float b00 = (q0.x+q0.y+q1.x+q1.y)*0.25f, b01 = (q0.z+q0.w+q1.z+q1.w)*0.25f;
    float b10 = (q2.x+q2.y+q3.x+q3.y)*0.25f, b11 = (q2.z+q2.w+q3.z+q3.w)*0.25f;
    float s2 = fabsf(a00-b00)+fabsf(a01-b01)+fabsf(a10-b10)+fabsf(a11-b11);
    float s4 = fabsf((a00+a01+a10+a11)*0.25f - (b00+b01+b10+b11)*0.25f);
    __shared__ float sb[8];
    float v;
    v = blockSum(s2, sb); if (threadIdx.x == 0) atomicAdd(&ws[3], v);
    v = blockSum(s4, sb); if (threadIdx.x == 0) atomicAdd(&ws[4], v);
}

// ---------- K3: color-curve segment sums (u32 LDS atomics, fixed-point) ----------
// 192 blocks: block = (slice 0..23) * 8 + part; each handles 8192 contiguous elems
__global__ __launch_bounds__(256) void k_curve(const float* __restrict__ pred,
                                               const float* __restrict__ targ,
                                               const float* __restrict__ inp,
                                               float* __restrict__ ws) {
    __shared__ unsigned h[288];            // [seg*3 + {cnt,ps,ts}]
    int tid = threadIdx.x;
    if (tid < 288) h[tid] = 0u;            // blockDim 256 -> need second pass
    if (tid < 32) h[256 + tid] = 0u;
    __syncthreads();
    int blk = blockIdx.x;
    int slice = blk >> 3, part = blk & 7;
    int c = slice % 3;
    int base = slice * HW + part * 8192;
    const float4* ip = (const float4*)(inp + base);
    const float4* pp = (const float4*)(pred + base);
    const float4* tp = (const float4*)(targ + base);
    int segbase = 32 * c;
    #pragma unroll
    for (int it = 0; it < 8; ++it) {
        float4 a = ip[it*256 + tid];
        float4 p = pp[it*256 + tid];
        float4 t = tp[it*256 + tid];
        float av[4] = {a.x, a.y, a.z, a.w};
        float pv[4] = {p.x, p.y, p.z, p.w};
        float tv[4] = {t.x, t.y, t.z, t.w};
        #pragma unroll
        for (int j = 0; j < 4; ++j) {
            int idx = (int)(av[j] * 32.f);
            idx = min(max(idx, 0), 31);
            unsigned s3 = (unsigned)((segbase + idx) * 3);
            atomicAdd(&h[s3],     1u);
            atomicAdd(&h[s3 + 1], (unsigned)__float2uint_rn(pv[j] * CURVE_SCALE));
            atomicAdd(&h[s3 + 2], (unsigned)__float2uint_rn(tv[j] * CURVE_SCALE));
        }
    }
    __syncthreads();
    if (tid < 96) {
        float cnt = (float)h[tid*3];
        if (cnt > 0.f) {
            atomicAdd(&ws[CURVE_CNT + tid], cnt);
            atomicAdd(&ws[CURVE_PS + tid], (float)h[tid*3+1] * (1.f/CURVE_SCALE));
            atomicAdd(&ws[CURVE_TS + tid], (float)h[tid*3+2] * (1.f/CURVE_SCALE));
        }
    }
}

// ---------- K4: soft histogram (thread-owns-bin) ----------
__global__ void k_hist(const float* __restrict__ pred, const float* __restrict__ targ,
                       float* __restrict__ ws) {
    int blk = blockIdx.x;          // 48*16
    int s = blk >> 4, part = blk & 15;
    const float* src = (s < 24 ? pred + s*HW : targ + (s-24)*HW) + part*4096;
    int bin = threadIdx.x & 63, qd = threadIdx.x >> 6;
    float cb = (float)bin * (1.f/63.f);
    float acc = 0.f;
    __shared__ float st[256];
    for (int tile = 0; tile < 16; ++tile) {
        __syncthreads();
        st[threadIdx.x] = src[tile*256 + threadIdx.x];
        __syncthreads();
        const float* xs = st + qd*64;
        #pragma unroll
        for (int j = 0; j < 64; ++j) {
            float d = xs[j] - cb;
            acc += __expf(-d*d*2048.f);   // 1/(2*bw^2), bw = 1/64
        }
    }
    __syncthreads();
    st[threadIdx.x] = acc;
    __syncthreads();
    if (threadIdx.x < 64) {
        float tot = st[threadIdx.x] + st[threadIdx.x+64] + st[threadIdx.x+128] + st[threadIdx.x+192];
        atomicAdd(&ws[HIST_OFF + s*64 + threadIdx.x], tot);
    }
}

// ---------- K5: horizontal 11-tap box sum on mask ----------
__global__ void k_blurh(float* __restrict__ ws) {
    int i = blockIdx.x*blockDim.x + threadIdx.x;  // NPX
    int x = i & 255;
    const float* m = ws + MASK_OFF;
    float s = 0.f;
    #pragma unroll
    for (int d = -5; d <= 5; ++d) {
        int xx = x + d;
        if (xx >= 0 && xx < 256) s += m[i - x + xx];
    }
    ws[TMP_OFF + i] = s;
}

// ---------- K6: vertical blur + window-boost accumulation ----------
__global__ void k_win(const float* __restrict__ pred, const float* __restrict__ targ,
                      float* __restrict__ ws) {
    int i = blockIdx.x*blockDim.x + threadIdx.x;
    int b = i >> 16, hw = i & 65535, y = hw >> 8;
    const float* tm = ws + TMP_OFF + b*HW;
    float s = 0.f;
    #pragma unroll
    for (int d = -5; d <= 5; ++d) {
        int yy = y + d;
        if (yy >= 0 && yy < 256) s += tm[hw + d*256];
    }
    float m = s * (1.f/121.f);
    const float* p = pred + b*3*HW + hw;
    const float* t = targ + b*3*HW + hw;
    float pr = p[0], pg = p[HW], pb = p[2*HW];
    float tr = t[0], tg = t[HW], tb = t[2*HW];
    float e3 = fabsf(pr-tr) + fabsf(pg-tg) + fabsf(pb-tb);
    float tmx = fmaxf(tr, fmaxf(tg, tb)), tmn = fminf(tr, fminf(tg, tb));
    float tsat = (tmx - tmn + 1e-7f) / (tmx + 1e-7f);
    float pmx = fmaxf(pr, fmaxf(pg, pb)), pmn = fminf(pr, fminf(pg, pb));
    float psat = (pmx - pmn + 1e-7f) / (pmx + 1e-7f);
    float sd = fabsf(psat - tsat);
    __shared__ float sb[8];
    float v;
    v = blockSum(e3*m, sb); if (threadIdx.x == 0) atomicAdd(&ws[7], v);
    v = blockSum(sd*m, sb); if (threadIdx.x == 0) atomicAdd(&ws[8], v);
    v = blockSum(m,    sb); if (threadIdx.x == 0) atomicAdd(&ws[9], v);
}

// ---------- K7: row FFT (real input -> 129 bins) ----------
__global__ __launch_bounds__(64) void k_fft_row(const float* __restrict__ pred,
                                                const float* __restrict__ targ,
                                                float* __restrict__ ws) {
    int bid = blockIdx.x;          // 48*256
    int s = bid >> 8, r = bid & 255;
    const float* src = (s < 24 ? pred + s*HW : targ + (s-24)*HW) + r*256;
    float2* out = (float2*)(ws + (s < 24 ? FFT_P + s*66048 : FFT_T + (s-24)*66048)) + r*129;
    __shared__ float2 a[256];
    int tid = threadIdx.x;
    #pragma unroll
    for (int j = 0; j < 4; ++j) {
        int i = tid + 64*j;
        a[__brev((unsigned)i) >> 24] = make_float2(src[i], 0.f);
    }
    __syncthreads();
    #pragma unroll
    for (int st = 0; st < 8; ++st) {
        int half = 1 << st, m = half << 1;
        #pragma unroll
        for (int k = 0; k < 2; ++k) {
            int bb = tid + 64*k;
            int j = bb & (half - 1);
            int i0 = ((bb >> st) << (st + 1)) + j;
            int i1 = i0 + half;
            float ang = -6.283185307f * (float)j / (float)m;
            float si, co;
            __sincosf(ang, &si, &co);
            float2 u = a[i0], v = a[i1];
            float2 w = make_float2(v.x*co - v.y*si, v.x*si + v.y*co);
            a[i0] = make_float2(u.x + w.x, u.y + w.y);
            a[i1] = make_float2(u.x - w.x, u.y - w.y);
        }
        __syncthreads();
    }
    out[tid] = a[tid];
    out[tid + 64] = a[tid + 64];
    if (tid == 0) out[128] = a[128];
}

// ---------- K8: column FFT, 8 columns x {P,T} per block ----------
__global__ __launch_bounds__(256) void k_fft_col(float* __restrict__ ws) {
    int bid = blockIdx.x;          // 24*17 = 408
    int s = bid / 17, kt = bid - s*17;
    int k0 = kt * 8;
    __shared__ float2 arr[16][257];   // [fid][elem], odd pad breaks conflicts
    __shared__ float sb[8];
    int tid = threadIdx.x;
    const float2* srcP = (const float2*)(ws + FFT_P) + s*33024;
    const float2* srcT = (const float2*)(ws + FFT_T) + s*33024;
    // coalesced load: 8 consecutive lanes read 8 consecutive columns of one row
    int kk = tid & 7, r0 = tid >> 3;          // r0: 0..31
    int col = k0 + kk;
    bool valid = (col <= 128);
    #pragma unroll
    for (int rb = 0; rb < 8; ++rb) {
        int r = r0 + rb*32;
        int br = __brev((unsigned)r) >> 24;
        float2 vp = valid ? srcP[r*129 + col] : make_float2(0.f, 0.f);
        arr[kk][br] = vp;
        float2 vt = valid ? srcT[r*129 + col] : make_float2(0.f, 0.f);
        arr[8 + kk][br] = vt;
    }
    __syncthreads();
    // 16 FFTs x 16 workers
    int fid = tid >> 4, w = tid & 15;
    float2* a = arr[fid];
    #pragma unroll
    for (int st = 0; st < 8; ++st) {
        int half = 1 << st, m = half << 1;
        #pragma unroll
        for (int q = 0; q < 8; ++q) {
            int b = w + (q << 4);       // 0..127
            int j = b & (half - 1);
            int i0 = ((b >> st) << (st + 1)) + j;
            int i1 = i0 + half;
            float ang = -6.283185307f * (float)j / (float)m;
            float si, co;
            __sincosf(ang, &si, &co);
            float2 u = a[i0], v = a[i1];
            float2 wv = make_float2(v.x*co - v.y*si, v.x*si + v.y*co);
            a[i0] = make_float2(u.x + wv.x, u.y + wv.y);
            a[i1] = make_float2(u.x - wv.x, u.y - wv.y);
        }
        __syncthreads();
    }
    // reduce |T|-|P| over the 8 valid columns
    float d1 = 0.f, d2 = 0.f;
    #pragma unroll
    for (int e = 0; e < 8; ++e) {
        int idx = tid + e*256;            // < 2048
        int k = idx >> 8, r = idx & 255;
        if (k0 + k <= 128) {
            float2 zp = arr[k][r], zt = arr[8 + k][r];
            float mp = sqrtf(zp.x*zp.x + zp.y*zp.y);
            float mt = sqrtf(zt.x*zt.x + zt.y*zt.y);
            float d = fabsf(mt - mp) * (1.f/256.f);
            d1 += d; d2 += d*d;
        }
    }
    float v;
    v = blockSum(d1, sb); if (tid == 0) atomicAdd(&ws[5], v);
    v = blockSum(d2, sb); if (tid == 0) atomicAdd(&ws[6], v);
}

// ---------- K9: final assembly ----------
__global__ void k_final(const float* __restrict__ ws, float* __restrict__ out) {
    __shared__ float red[256];
    int tid = threadIdx.x;
    // curve
    float cv = 0.f;
    if (tid < 96) {
        float cnt = ws[CURVE_CNT + tid];
        if (cnt > 0.f) cv = fabsf(ws[CURVE_PS + tid] - ws[CURVE_TS + tid]) / cnt;
    }
    red[tid] = cv;
    __syncthreads();
    for (int o = 128; o > 0; o >>= 1) { if (tid < o) red[tid] += red[tid + o]; __syncthreads(); }
    float curve = red[0] / 96.f;
    __syncthreads();
    // histogram EMD
    float hacc = 0.f;
    if (tid < 24) {
        const float* hp = ws + HIST_OFF + tid*64;
        const float* ht = ws + HIST_OFF + (24 + tid)*64;
        float sp = 0.f, stt = 0.f;
        for (int k = 0; k < 64; ++k) { sp += hp[k]; stt += ht[k]; }
        float ip = 1.f / (sp + 1e-7f), it = 1.f / (stt + 1e-7f);
        float cp = 0.f, ct = 0.f;
        for (int k = 0; k < 64; ++k) {
            cp += hp[k] * ip;
            ct += ht[k] * it;
            hacc += fabsf(cp - ct);
        }
    }
    red[tid] = hacc;
    __syncthreads();
    for (int o = 128; o > 0; o >>= 1) { if (tid < o) red[tid] += red[tid + o]; __syncthreads(); }
    float hl = red[0] / 1536.f;
    if (tid == 0) {
        float l1  = ws[0] / (float)NEL;
        float lab = (ws[1] / (float)NPX) * 0.01f + 2.f * (ws[2] / (2.f * (float)NPX * 128.f));
        float ms  = (l1 + ws[3] / 393216.f + ws[4] / 98304.f) * (1.f/3.f);
        const float M = 792576.f;
        float ff  = (ws[6] / M) / (ws[5] / M + 1e-8f);
        float wm  = ws[9];
        float wb  = ws[7] / (wm*3.f + 1e-7f) + 0.5f * (ws[8] / (wm + 1e-7f));
        out[0] = l1 + 0.3f*ff + 0.4f*lab + 0.3f*ms + 0.4f*curve + 0.2f*hl + 0.5f*wb;
    }
}

extern "C" void kernel_launch(void* const* d_in, const int* in_sizes, int n_in,
                              void* d_out, int out_size, void* d_ws, size_t ws_size,
                              hipStream_t stream) {
    const float* pred = (const float*)d_in[0];
    const float* targ = (const float*)d_in[1];
    const float* inp  = (const float*)d_in[2];
    float* ws = (float*)d_ws;
    float* out = (float*)d_out;

    hipMemsetAsync(d_ws, 0, ZERO_FLOATS * sizeof(float), stream);

    // mask pipeline first (its scratch is overwritten by the FFT buffers)
    k_point  <<<2048, 256, 0, stream>>>(pred, targ, ws);
    k_blurh  <<<2048, 256, 0, stream>>>(ws);
    k_win    <<<2048, 256, 0, stream>>>(pred, targ, ws);
    // independent reductions
    k_ms     <<<384,  256, 0, stream>>>(pred, targ, ws);
    k_curve  <<<192,  256, 0, stream>>>(pred, targ, inp, ws);
    k_hist   <<<768,  256, 0, stream>>>(pred, targ, ws);
    // FFT (reuses mask/tmp scratch region)
    k_fft_row<<<12288, 64, 0, stream>>>(pred, targ, ws);
    k_fft_col<<<408,  256, 0, stream>>>(ws);
    k_final  <<<1,    256, 0, stream>>>(ws, out);
}

// Round 7
// 279.103 us; speedup vs baseline: 1.3523x; 1.0103x over previous
//
#include <hip/hip_runtime.h>
#include <math.h>

#define HW 65536
#define NPX 524288      // 8*256*256
#define NEL 1572864     // 8*3*256*256

// ---- ws layout (float offsets) ----
#define ACC_OFF   0      // scalars: 0 l1,1 sL,2 sab,3 S2,4 S4,5 d1,6 d2,7 wnum,8 wsat,9 wm
#define CURVE_CNT 16     // 96
#define CURVE_PS  112    // 96
#define CURVE_TS  208    // 96
#define HIST_OFF  304    // 48*64 = 3072 -> ends at 3376
#define ZERO_FLOATS 3376
// mask/blur scratch (used first, then overwritten by FFT buffers)
#define MASK_OFF  4096
#define TMP_OFF   (4096 + 524288)
// FFT buffers OVERLAP mask/tmp (stream ordering: mask pipeline done first)
#define FFT_P     4096                      // 24 slices * 66048 floats
#define FFT_T     (FFT_P + 24*66048)
// total floats = FFT_T + 24*66048 = 3,174,400  (~12.7 MB)

#define CURVE_SCALE 131072.0f     // 2^17 fixed-point; 8192 elems/block * 2^17 = 2^30 < u32 max

// ---------- fast transcendentals (args strictly positive on use) ----------
__device__ __forceinline__ float fpow24(float x) {     // x^2.4, x > 0.04045
    return __builtin_amdgcn_exp2f(2.4f * __builtin_amdgcn_logf(x));
}
__device__ __forceinline__ float fcbrt(float x) {      // x^(1/3), x > 0.0088
    return __builtin_amdgcn_exp2f((1.0f/3.0f) * __builtin_amdgcn_logf(x));
}

// ---------- helpers ----------
__device__ __forceinline__ float labF(float t) {
    return t > 0.008856452f ? fcbrt(t) : t * 7.787037f + 0.13793103f;
}

__device__ __forceinline__ void rgb2lab(float r, float g, float b,
                                        float& L, float& A, float& Bc) {
    float lr = r > 0.04045f ? fpow24((r + 0.055f) * (1.0f/1.055f)) : r * (1.0f/12.92f);
    float lg = g > 0.04045f ? fpow24((g + 0.055f) * (1.0f/1.055f)) : g * (1.0f/12.92f);
    float lb = b > 0.04045f ? fpow24((b + 0.055f) * (1.0f/1.055f)) : b * (1.0f/12.92f);
    float X = (0.4124564f*lr + 0.3575761f*lg + 0.1804375f*lb) * (1.0f/0.95047f);
    float Y = (0.2126729f*lr + 0.7151522f*lg + 0.0721750f*lb);
    float Z = (0.0193339f*lr + 0.1191920f*lg + 0.9503041f*lb) * (1.0f/1.08883f);
    float fx = labF(X), fy = labF(Y), fz = labF(Z);
    L = 116.f*fy - 16.f;
    A = 500.f*(fx - fy);
    Bc = 200.f*(fy - fz);
}

// block-wide sum; returns total on thread 0 (0 elsewhere); ends with barrier
__device__ __forceinline__ float blockSum(float v, float* sb) {
    #pragma unroll
    for (int o = 32; o > 0; o >>= 1) v += __shfl_down(v, o, 64);
    int lane = threadIdx.x & 63, w = threadIdx.x >> 6;
    if (lane == 0) sb[w] = v;
    __syncthreads();
    float r = 0.f;
    if (threadIdx.x == 0) {
        int nw = (blockDim.x + 63) >> 6;
        for (int i = 0; i < nw; ++i) r += sb[i];
    }
    __syncthreads();
    return r;
}

// ---------- K1: pointwise (L1, LAB, target mask) ----------
__global__ void k_point(const float* __restrict__ pred, const float* __restrict__ targ,
                        float* __restrict__ ws) {
    int i = blockIdx.x * blockDim.x + threadIdx.x;   // < NPX
    int b = i >> 16, hw = i & 65535;
    const float* p = pred + b*3*HW + hw;
    const float* t = targ + b*3*HW + hw;
    float pr = p[0], pg = p[HW], pb = p[2*HW];
    float tr = t[0], tg = t[HW], tb = t[2*HW];
    float e3 = fabsf(pr-tr) + fabsf(pg-tg) + fabsf(pb-tb);
    float Lp,Ap,Bp, Lt,At,Bt;
    rgb2lab(pr,pg,pb, Lp,Ap,Bp);
    rgb2lab(tr,tg,tb, Lt,At,Bt);
    float sL = fabsf(Lp-Lt);
    float sab = fabsf(Ap-At) + fabsf(Bp-Bt);
    float tmx = fmaxf(tr, fmaxf(tg, tb)), tmn = fminf(tr, fminf(tg, tb));
    float tsat = (tmx - tmn + 1e-7f) / (tmx + 1e-7f);
    ws[MASK_OFF + i] = (tmx > 0.6f && tsat > 0.2f) ? 1.f : 0.f;
    __shared__ float sb[8];
    float v;
    v = blockSum(e3, sb);  if (threadIdx.x == 0) atomicAdd(&ws[0], v);
    v = blockSum(sL, sb);  if (threadIdx.x == 0) atomicAdd(&ws[1], v);
    v = blockSum(sab, sb); if (threadIdx.x == 0) atomicAdd(&ws[2], v);
}

// ---------- K2: multi-scale pooled L1 ----------
__global__ void k_ms(const float* __restrict__ pred, const float* __restrict__ targ,
                     float* __restrict__ ws) {
    int t = blockIdx.x * blockDim.x + threadIdx.x;   // < 98304
    int sc = t >> 12;              // (b,c) slice 0..23
    int q = t & 4095;
    int y4 = q >> 6, x4 = q & 63;
    const float* pp = pred + sc*HW + (y4*4)*256 + x4*4;
    const float* tp = targ + sc*HW + (y4*4)*256 + x4*4;
    float4 p0 = *(const float4*)(pp);
    float4 p1 = *(const float4*)(pp + 256);
    float4 p2 = *(const float4*)(pp + 512);
    float4 p3 = *(const float4*)(pp + 768);
    float4 q0 = *(const float4*)(tp);
    float4 q1 = *(const float4*)(tp + 256);
    float4 q2 = *(const float4*)(tp + 512);
    float4 q3 = *(const float4*)(tp + 768);
    float a00 = (p0.x+p0.y+p1.x+p1.y)*0.25f, a01 = (p0.z+p0.w+p1.z+p1.w)*0.25f;
    float a10 = (p2.x+p2.y+p3.x+p3.y)*0.25f, a11 = (p2.z+p2.w+p3.z+p3.w)*0.25f;
    float b00 = (q0.x+q0.y+q1.x+q1.y)*0.25f, b01 = (q0.z+q0.w+q1.z+q1.w)*0.25f;
    float b10 = (q2.x+q2.y+q3.x+q3.y)*0.25f, b11 = (q2.z+q2.w+q3.z+q3.w)*0.25f;
    float s2 = fabsf(a00-b00)+fabsf(a01-b01)+fabsf(a10-b10)+fabsf(a11-b11);
    float s4 = fabsf((a00+a01+a10+a11)*0.25f - (b00+b01+b10+b11)*0.25f);
    __shared__ float sb[8];
    float v;
    v = blockSum(s2, sb); if (threadIdx.x == 0) atomicAdd(&ws[3], v);
    v = blockSum(s4, sb); if (threadIdx.x == 0) atomicAdd(&ws[4], v);
}

// ---------- K3: color-curve segment sums (u32 LDS atomics, fixed-point) ----------
// 192 blocks: block = (slice 0..23) * 8 + part; each handles 8192 contiguous elems
__global__ __launch_bounds__(256) void k_curve(const float* __restrict__ pred,
                                               const float* __restrict__ targ,
                                               const float* __restrict__ inp,
                                               float* __restrict__ ws) {
    __shared__ unsigned h[288];            // [seg*3 + {cnt,ps,ts}]
    int tid = threadIdx.x;
    if (tid < 288) h[tid] = 0u;            // blockDim 256 -> need second pass
    if (tid < 32) h[256 + tid] = 0u;
    __syncthreads();
    int blk = blockIdx.x;
    int slice = blk >> 3, part = blk & 7;
    int c = slice % 3;
    int base = slice * HW + part * 8192;
    const float4* ip = (const float4*)(inp + base);
    const float4* pp = (const float4*)(pred + base);
    const float4* tp = (const float4*)(targ + base);
    int segbase = 32 * c;
    #pragma unroll
    for (int it = 0; it < 8; ++it) {
        float4 a = ip[it*256 + tid];
        float4 p = pp[it*256 + tid];
        float4 t = tp[it*256 + tid];
        float av[4] = {a.x, a.y, a.z, a.w};
        float pv[4] = {p.x, p.y, p.z, p.w};
        float tv[4] = {t.x, t.y, t.z, t.w};
        #pragma unroll
        for (int j = 0; j < 4; ++j) {
            int idx = (int)(av[j] * 32.f);
            idx = min(max(idx, 0), 31);
            unsigned s3 = (unsigned)((segbase + idx) * 3);
            atomicAdd(&h[s3],     1u);
            atomicAdd(&h[s3 + 1], (unsigned)__float2uint_rn(pv[j] * CURVE_SCALE));
            atomicAdd(&h[s3 + 2], (unsigned)__float2uint_rn(tv[j] * CURVE_SCALE));
        }
    }
    __syncthreads();
    if (tid < 96) {
        float cnt = (float)h[tid*3];
        if (cnt > 0.f) {
            atomicAdd(&ws[CURVE_CNT + tid], cnt);
            atomicAdd(&ws[CURVE_PS + tid], (float)h[tid*3+1] * (1.f/CURVE_SCALE));
            atomicAdd(&ws[CURVE_TS + tid], (float)h[tid*3+2] * (1.f/CURVE_SCALE));
        }
    }
}

// ---------- K4: soft histogram (thread-owns-bin) ----------
__global__ void k_hist(const float* __restrict__ pred, const float* __restrict__ targ,
                       float* __restrict__ ws) {
    int blk = blockIdx.x;          // 48*16
    int s = blk >> 4, part = blk & 15;
    const float* src = (s < 24 ? pred + s*HW : targ + (s-24)*HW) + part*4096;
    int bin = threadIdx.x & 63, qd = threadIdx.x >> 6;
    float cb = (float)bin * (1.f/63.f);
    float acc = 0.f;
    __shared__ float st[256];
    for (int tile = 0; tile < 16; ++tile) {
        __syncthreads();
        st[threadIdx.x] = src[tile*256 + threadIdx.x];
        __syncthreads();
        const float* xs = st + qd*64;
        #pragma unroll
        for (int j = 0; j < 64; ++j) {
            float d = xs[j] - cb;
            acc += __expf(-d*d*2048.f);   // 1/(2*bw^2), bw = 1/64
        }
    }
    __syncthreads();
    st[threadIdx.x] = acc;
    __syncthreads();
    if (threadIdx.x < 64) {
        float tot = st[threadIdx.x] + st[threadIdx.x+64] + st[threadIdx.x+128] + st[threadIdx.x+192];
        atomicAdd(&ws[HIST_OFF + s*64 + threadIdx.x], tot);
    }
}

// ---------- K5: horizontal 11-tap box sum on mask ----------
__global__ void k_blurh(float* __restrict__ ws) {
    int i = blockIdx.x*blockDim.x + threadIdx.x;  // NPX
    int x = i & 255;
    const float* m = ws + MASK_OFF;
    float s = 0.f;
    #pragma unroll
    for (int d = -5; d <= 5; ++d) {
        int xx = x + d;
        if (xx >= 0 && xx < 256) s += m[i - x + xx];
    }
    ws[TMP_OFF + i] = s;
}

// ---------- K6: vertical blur + window-boost accumulation ----------
__global__ void k_win(const float* __restrict__ pred, const float* __restrict__ targ,
                      float* __restrict__ ws) {
    int i = blockIdx.x*blockDim.x + threadIdx.x;
    int b = i >> 16, hw = i & 65535, y = hw >> 8;
    const float* tm = ws + TMP_OFF + b*HW;
    float s = 0.f;
    #pragma unroll
    for (int d = -5; d <= 5; ++d) {
        int yy = y + d;
        if (yy >= 0 && yy < 256) s += tm[hw + d*256];
    }
    float m = s * (1.f/121.f);
    const float* p = pred + b*3*HW + hw;
    const float* t = targ + b*3*HW + hw;
    float pr = p[0], pg = p[HW], pb = p[2*HW];
    float tr = t[0], tg = t[HW], tb = t[2*HW];
    float e3 = fabsf(pr-tr) + fabsf(pg-tg) + fabsf(pb-tb);
    float tmx = fmaxf(tr, fmaxf(tg, tb)), tmn = fminf(tr, fminf(tg, tb));
    float tsat = (tmx - tmn + 1e-7f) / (tmx + 1e-7f);
    float pmx = fmaxf(pr, fmaxf(pg, pb)), pmn = fminf(pr, fminf(pg, pb));
    float psat = (pmx - pmn + 1e-7f) / (pmx + 1e-7f);
    float sd = fabsf(psat - tsat);
    __shared__ float sb[8];
    float v;
    v = blockSum(e3*m, sb); if (threadIdx.x == 0) atomicAdd(&ws[7], v);
    v = blockSum(sd*m, sb); if (threadIdx.x == 0) atomicAdd(&ws[8], v);
    v = blockSum(m,    sb); if (threadIdx.x == 0) atomicAdd(&ws[9], v);
}

// ---------- K7: row FFT (real input -> 129 bins) ----------
__global__ __launch_bounds__(64) void k_fft_row(const float* __restrict__ pred,
                                                const float* __restrict__ targ,
                                                float* __restrict__ ws) {
    int bid = blockIdx.x;          // 48*256
    int s = bid >> 8, r = bid & 255;
    const float* src = (s < 24 ? pred + s*HW : targ + (s-24)*HW) + r*256;
    float2* out = (float2*)(ws + (s < 24 ? FFT_P + s*66048 : FFT_T + (s-24)*66048)) + r*129;
    __shared__ float2 a[256];
    int tid = threadIdx.x;
    #pragma unroll
    for (int j = 0; j < 4; ++j) {
        int i = tid + 64*j;
        a[__brev((unsigned)i) >> 24] = make_float2(src[i], 0.f);
    }
    __syncthreads();
    #pragma unroll
    for (int st = 0; st < 8; ++st) {
        int half = 1 << st, m = half << 1;
        #pragma unroll
        for (int k = 0; k < 2; ++k) {
            int bb = tid + 64*k;
            int j = bb & (half - 1);
            int i0 = ((bb >> st) << (st + 1)) + j;
            int i1 = i0 + half;
            float ang = -6.283185307f * (float)j / (float)m;
            float si, co;
            __sincosf(ang, &si, &co);
            float2 u = a[i0], v = a[i1];
            float2 w = make_float2(v.x*co - v.y*si, v.x*si + v.y*co);
            a[i0] = make_float2(u.x + w.x, u.y + w.y);
            a[i1] = make_float2(u.x - w.x, u.y - w.y);
        }
        __syncthreads();
    }
    out[tid] = a[tid];
    out[tid + 64] = a[tid + 64];
    if (tid == 0) out[128] = a[128];
}

// ---------- K8: column FFT, 8 columns x {P,T} per block ----------
__global__ __launch_bounds__(256) void k_fft_col(float* __restrict__ ws) {
    int bid = blockIdx.x;          // 24*17 = 408
    int s = bid / 17, kt = bid - s*17;
    int k0 = kt * 8;
    __shared__ float2 arr[16][257];   // [fid][elem], odd pad breaks conflicts
    __shared__ float sb[8];
    int tid = threadIdx.x;
    const float2* srcP = (const float2*)(ws + FFT_P) + s*33024;
    const float2* srcT = (const float2*)(ws + FFT_T) + s*33024;
    // coalesced load: 8 consecutive lanes read 8 consecutive columns of one row
    int kk = tid & 7, r0 = tid >> 3;          // r0: 0..31
    int col = k0 + kk;
    bool valid = (col <= 128);
    #pragma unroll
    for (int rb = 0; rb < 8; ++rb) {
        int r = r0 + rb*32;
        int br = __brev((unsigned)r) >> 24;
        float2 vp = valid ? srcP[r*129 + col] : make_float2(0.f, 0.f);
        arr[kk][br] = vp;
        float2 vt = valid ? srcT[r*129 + col] : make_float2(0.f, 0.f);
        arr[8 + kk][br] = vt;
    }
    __syncthreads();
    // 16 FFTs x 16 workers
    int fid = tid >> 4, w = tid & 15;
    float2* a = arr[fid];
    #pragma unroll
    for (int st = 0; st < 8; ++st) {
        int half = 1 << st, m = half << 1;
        #pragma unroll
        for (int q = 0; q < 8; ++q) {
            int b = w + (q << 4);       // 0..127
            int j = b & (half - 1);
            int i0 = ((b >> st) << (st + 1)) + j;
            int i1 = i0 + half;
            float ang = -6.283185307f * (float)j / (float)m;
            float si, co;
            __sincosf(ang, &si, &co);
            float2 u = a[i0], v = a[i1];
            float2 wv = make_float2(v.x*co - v.y*si, v.x*si + v.y*co);
            a[i0] = make_float2(u.x + wv.x, u.y + wv.y);
            a[i1] = make_float2(u.x - wv.x, u.y - wv.y);
        }
        __syncthreads();
    }
    // reduce |T|-|P| over the 8 valid columns
    float d1 = 0.f, d2 = 0.f;
    #pragma unroll
    for (int e = 0; e < 8; ++e) {
        int idx = tid + e*256;            // < 2048
        int k = idx >> 8, r = idx & 255;
        if (k0 + k <= 128) {
            float2 zp = arr[k][r], zt = arr[8 + k][r];
            float mp = sqrtf(zp.x*zp.x + zp.y*zp.y);
            float mt = sqrtf(zt.x*zt.x + zt.y*zt.y);
            float d = fabsf(mt - mp) * (1.f/256.f);
            d1 += d; d2 += d*d;
        }
    }
    float v;
    v = blockSum(d1, sb); if (tid == 0) atomicAdd(&ws[5], v);
    v = blockSum(d2, sb); if (tid == 0) atomicAdd(&ws[6], v);
}

// ---------- K9: final assembly ----------
__global__ void k_final(const float* __restrict__ ws, float* __restrict__ out) {
    __shared__ float red[256];
    int tid = threadIdx.x;
    // curve
    float cv = 0.f;
    if (tid < 96) {
        float cnt = ws[CURVE_CNT + tid];
        if (cnt > 0.f) cv = fabsf(ws[CURVE_PS + tid] - ws[CURVE_TS + tid]) / cnt;
    }
    red[tid] = cv;
    __syncthreads();
    for (int o = 128; o > 0; o >>= 1) { if (tid < o) red[tid] += red[tid + o]; __syncthreads(); }
    float curve = red[0] / 96.f;
    __syncthreads();
    // histogram EMD
    float hacc = 0.f;
    if (tid < 24) {
        const float* hp = ws + HIST_OFF + tid*64;
        const float* ht = ws + HIST_OFF + (24 + tid)*64;
        float sp = 0.f, stt = 0.f;
        for (int k = 0; k < 64; ++k) { sp += hp[k]; stt += ht[k]; }
        float ip = 1.f / (sp + 1e-7f), it = 1.f / (stt + 1e-7f);
        float cp = 0.f, ct = 0.f;
        for (int k = 0; k < 64; ++k) {
            cp += hp[k] * ip;
            ct += ht[k] * it;
            hacc += fabsf(cp - ct);
        }
    }
    red[tid] = hacc;
    __syncthreads();
    for (int o = 128; o > 0; o >>= 1) { if (tid < o) red[tid] += red[tid + o]; __syncthreads(); }
    float hl = red[0] / 1536.f;
    if (tid == 0) {
        float l1  = ws[0] / (float)NEL;
        float lab = (ws[1] / (float)NPX) * 0.01f + 2.f * (ws[2] / (2.f * (float)NPX * 128.f));
        float ms  = (l1 + ws[3] / 393216.f + ws[4] / 98304.f) * (1.f/3.f);
        const float M = 792576.f;
        float ff  = (ws[6] / M) / (ws[5] / M + 1e-8f);
        float wm  = ws[9];
        float wb  = ws[7] / (wm*3.f + 1e-7f) + 0.5f * (ws[8] / (wm + 1e-7f));
        out[0] = l1 + 0.3f*ff + 0.4f*lab + 0.3f*ms + 0.4f*curve + 0.2f*hl + 0.5f*wb;
    }
}

extern "C" void kernel_launch(void* const* d_in, const int* in_sizes, int n_in,
                              void* d_out, int out_size, void* d_ws, size_t ws_size,
                              hipStream_t stream) {
    const float* pred = (const float*)d_in[0];
    const float* targ = (const float*)d_in[1];
    const float* inp  = (const float*)d_in[2];
    float* ws = (float*)d_ws;
    float* out = (float*)d_out;

    hipMemsetAsync(d_ws, 0, ZERO_FLOATS * sizeof(float), stream);

    // mask pipeline first (its scratch is overwritten by the FFT buffers)
    k_point  <<<2048, 256, 0, stream>>>(pred, targ, ws);
    k_blurh  <<<2048, 256, 0, stream>>>(ws);
    k_win    <<<2048, 256, 0, stream>>>(pred, targ, ws);
    // independent reductions
    k_ms     <<<384,  256, 0, stream>>>(pred, targ, ws);
    k_curve  <<<192,  256, 0, stream>>>(pred, targ, inp, ws);
    k_hist   <<<768,  256, 0, stream>>>(pred, targ, ws);
    // FFT (reuses mask/tmp scratch region)
    k_fft_row<<<12288, 64, 0, stream>>>(pred, targ, ws);
    k_fft_col<<<408,  256, 0, stream>>>(ws);
    k_final  <<<1,    256, 0, stream>>>(ws, out);
}

// Round 8
// 124.687 us; speedup vs baseline: 3.0270x; 2.2384x over previous
//
#include <hip/hip_runtime.h>
#include <math.h>

#define HW 65536
#define NPX 524288      // 8*256*256
#define NEL 1572864     // 8*3*256*256

// ---- ws layout (float offsets) ----
#define CURVE_CNT 16     // 96
#define CURVE_PS  112    // 96
#define CURVE_TS  208    // 96
#define HIST_OFF  304    // 48*64 = 3072 -> ends at 3376
#define ZERO_FLOATS 3376
// per-block partial arrays (no atomics; every slot written each call)
#define P_POINT   4096                  // 3 x 2048  -> ends 10240
#define P_MS      10240                 // 2 x 384   -> ends 11008
#define P_WIN     11008                 // 3 x 2048  -> ends 17152
#define P_FFT     17152                 // 2 x 408   -> ends 17968
// mask/blur scratch (used first, then overwritten by FFT buffers)
#define MASK_OFF  18432
#define TMP_OFF   (18432 + 524288)
// FFT buffers OVERLAP mask/tmp (stream ordering: mask pipeline done first)
#define FFT_P     18432                 // 24 slices * 66048 floats
#define FFT_T     (FFT_P + 24*66048)
// total floats = FFT_T + 24*66048 = 3,188,736  (~12.8 MB)

#define CURVE_SCALE 131072.0f     // 2^17 fixed-point; 8192 elems/block * 2^17 = 2^30 < u32 max

// ---------- fast transcendentals (args strictly positive on use) ----------
__device__ __forceinline__ float fpow24(float x) {     // x^2.4, x > 0.04045
    return __builtin_amdgcn_exp2f(2.4f * __builtin_amdgcn_logf(x));
}
__device__ __forceinline__ float fcbrt(float x) {      // x^(1/3), x > 0.0088
    return __builtin_amdgcn_exp2f((1.0f/3.0f) * __builtin_amdgcn_logf(x));
}

// ---------- helpers ----------
__device__ __forceinline__ float labF(float t) {
    return t > 0.008856452f ? fcbrt(t) : t * 7.787037f + 0.13793103f;
}

__device__ __forceinline__ void rgb2lab(float r, float g, float b,
                                        float& L, float& A, float& Bc) {
    float lr = r > 0.04045f ? fpow24((r + 0.055f) * (1.0f/1.055f)) : r * (1.0f/12.92f);
    float lg = g > 0.04045f ? fpow24((g + 0.055f) * (1.0f/1.055f)) : g * (1.0f/12.92f);
    float lb = b > 0.04045f ? fpow24((b + 0.055f) * (1.0f/1.055f)) : b * (1.0f/12.92f);
    float X = (0.4124564f*lr + 0.3575761f*lg + 0.1804375f*lb) * (1.0f/0.95047f);
    float Y = (0.2126729f*lr + 0.7151522f*lg + 0.0721750f*lb);
    float Z = (0.0193339f*lr + 0.1191920f*lg + 0.9503041f*lb) * (1.0f/1.08883f);
    float fx = labF(X), fy = labF(Y), fz = labF(Z);
    L = 116.f*fy - 16.f;
    A = 500.f*(fx - fy);
    Bc = 200.f*(fy - fz);
}

// block-wide sum; returns total on thread 0 (0 elsewhere); ends with barrier
__device__ __forceinline__ float blockSum(float v, float* sb) {
    #pragma unroll
    for (int o = 32; o > 0; o >>= 1) v += __shfl_down(v, o, 64);
    int lane = threadIdx.x & 63, w = threadIdx.x >> 6;
    if (lane == 0) sb[w] = v;
    __syncthreads();
    float r = 0.f;
    if (threadIdx.x == 0) {
        int nw = (blockDim.x + 63) >> 6;
        for (int i = 0; i < nw; ++i) r += sb[i];
    }
    __syncthreads();
    return r;
}

// ---------- K1: pointwise (L1, LAB, target mask) -> per-block partials ----------
__global__ void k_point(const float* __restrict__ pred, const float* __restrict__ targ,
                        float* __restrict__ ws) {
    int i = blockIdx.x * blockDim.x + threadIdx.x;   // < NPX
    int b = i >> 16, hw = i & 65535;
    const float* p = pred + b*3*HW + hw;
    const float* t = targ + b*3*HW + hw;
    float pr = p[0], pg = p[HW], pb = p[2*HW];
    float tr = t[0], tg = t[HW], tb = t[2*HW];
    float e3 = fabsf(pr-tr) + fabsf(pg-tg) + fabsf(pb-tb);
    float Lp,Ap,Bp, Lt,At,Bt;
    rgb2lab(pr,pg,pb, Lp,Ap,Bp);
    rgb2lab(tr,tg,tb, Lt,At,Bt);
    float sL = fabsf(Lp-Lt);
    float sab = fabsf(Ap-At) + fabsf(Bp-Bt);
    float tmx = fmaxf(tr, fmaxf(tg, tb)), tmn = fminf(tr, fminf(tg, tb));
    float tsat = (tmx - tmn + 1e-7f) / (tmx + 1e-7f);
    ws[MASK_OFF + i] = (tmx > 0.6f && tsat > 0.2f) ? 1.f : 0.f;
    __shared__ float sb[8];
    float v;
    v = blockSum(e3, sb);  if (threadIdx.x == 0) ws[P_POINT + blockIdx.x] = v;
    v = blockSum(sL, sb);  if (threadIdx.x == 0) ws[P_POINT + 2048 + blockIdx.x] = v;
    v = blockSum(sab, sb); if (threadIdx.x == 0) ws[P_POINT + 4096 + blockIdx.x] = v;
}

// ---------- K2: multi-scale pooled L1 -> partials ----------
__global__ void k_ms(const float* __restrict__ pred, const float* __restrict__ targ,
                     float* __restrict__ ws) {
    int t = blockIdx.x * blockDim.x + threadIdx.x;   // < 98304
    int sc = t >> 12;              // (b,c) slice 0..23
    int q = t & 4095;
    int y4 = q >> 6, x4 = q & 63;
    const float* pp = pred + sc*HW + (y4*4)*256 + x4*4;
    const float* tp = targ + sc*HW + (y4*4)*256 + x4*4;
    float4 p0 = *(const float4*)(pp);
    float4 p1 = *(const float4*)(pp + 256);
    float4 p2 = *(const float4*)(pp + 512);
    float4 p3 = *(const float4*)(pp + 768);
    float4 q0 = *(const float4*)(tp);
    float4 q1 = *(const float4*)(tp + 256);
    float4 q2 = *(const float4*)(tp + 512);
    float4 q3 = *(const float4*)(tp + 768);
    float a00 = (p0.x+p0.y+p1.x+p1.y)*0.25f, a01 = (p0.z+p0.w+p1.z+p1.w)*0.25f;
    float a10 = (p2.x+p2.y+p3.x+p3.y)*0.25f, a11 = (p2.z+p2.w+p3.z+p3.w)*0.25f;
    float b00 = (q0.x+q0.y+q1.x+q1.y)*0.25f, b01 = (q0.z+q0.w+q1.z+q1.w)*0.25f;
    float b10 = (q2.x+q2.y+q3.x+q3.y)*0.25f, b11 = (q2.z+q2.w+q3.z+q3.w)*0.25f;
    float s2 = fabsf(a00-b00)+fabsf(a01-b01)+fabsf(a10-b10)+fabsf(a11-b11);
    float s4 = fabsf((a00+a01+a10+a11)*0.25f - (b00+b01+b10+b11)*0.25f);
    __shared__ float sb[8];
    float v;
    v = blockSum(s2, sb); if (threadIdx.x == 0) ws[P_MS + blockIdx.x] = v;
    v = blockSum(s4, sb); if (threadIdx.x == 0) ws[P_MS + 384 + blockIdx.x] = v;
}

// ---------- K3: color-curve segment sums (u32 LDS atomics, fixed-point) ----------
// 192 blocks: block = (slice 0..23) * 8 + part; each handles 8192 contiguous elems
__global__ __launch_bounds__(256) void k_curve(const float* __restrict__ pred,
                                               const float* __restrict__ targ,
                                               const float* __restrict__ inp,
                                               float* __restrict__ ws) {
    __shared__ unsigned h[288];            // [seg*3 + {cnt,ps,ts}]
    int tid = threadIdx.x;
    if (tid < 288) h[tid] = 0u;
    if (tid < 32) h[256 + tid] = 0u;
    __syncthreads();
    int blk = blockIdx.x;
    int slice = blk >> 3, part = blk & 7;
    int c = slice % 3;
    int base = slice * HW + part * 8192;
    const float4* ip = (const float4*)(inp + base);
    const float4* pp = (const float4*)(pred + base);
    const float4* tp = (const float4*)(targ + base);
    int segbase = 32 * c;
    #pragma unroll
    for (int it = 0; it < 8; ++it) {
        float4 a = ip[it*256 + tid];
        float4 p = pp[it*256 + tid];
        float4 t = tp[it*256 + tid];
        float av[4] = {a.x, a.y, a.z, a.w};
        float pv[4] = {p.x, p.y, p.z, p.w};
        float tv[4] = {t.x, t.y, t.z, t.w};
        #pragma unroll
        for (int j = 0; j < 4; ++j) {
            int idx = (int)(av[j] * 32.f);
            idx = min(max(idx, 0), 31);
            unsigned s3 = (unsigned)((segbase + idx) * 3);
            atomicAdd(&h[s3],     1u);
            atomicAdd(&h[s3 + 1], (unsigned)__float2uint_rn(pv[j] * CURVE_SCALE));
            atomicAdd(&h[s3 + 2], (unsigned)__float2uint_rn(tv[j] * CURVE_SCALE));
        }
    }
    __syncthreads();
    if (tid < 96) {
        float cnt = (float)h[tid*3];
        if (cnt > 0.f) {
            atomicAdd(&ws[CURVE_CNT + tid], cnt);
            atomicAdd(&ws[CURVE_PS + tid], (float)h[tid*3+1] * (1.f/CURVE_SCALE));
            atomicAdd(&ws[CURVE_TS + tid], (float)h[tid*3+2] * (1.f/CURVE_SCALE));
        }
    }
}

// ---------- K4: soft histogram (thread-owns-bin) ----------
__global__ void k_hist(const float* __restrict__ pred, const float* __restrict__ targ,
                       float* __restrict__ ws) {
    int blk = blockIdx.x;          // 48*16
    int s = blk >> 4, part = blk & 15;
    const float* src = (s < 24 ? pred + s*HW : targ + (s-24)*HW) + part*4096;
    int bin = threadIdx.x & 63, qd = threadIdx.x >> 6;
    float cb = (float)bin * (1.f/63.f);
    float acc = 0.f;
    __shared__ float st[256];
    for (int tile = 0; tile < 16; ++tile) {
        __syncthreads();
        st[threadIdx.x] = src[tile*256 + threadIdx.x];
        __syncthreads();
        const float* xs = st + qd*64;
        #pragma unroll
        for (int j = 0; j < 64; ++j) {
            float d = xs[j] - cb;
            acc += __expf(-d*d*2048.f);   // 1/(2*bw^2), bw = 1/64
        }
    }
    __syncthreads();
    st[threadIdx.x] = acc;
    __syncthreads();
    if (threadIdx.x < 64) {
        float tot = st[threadIdx.x] + st[threadIdx.x+64] + st[threadIdx.x+128] + st[threadIdx.x+192];
        atomicAdd(&ws[HIST_OFF + s*64 + threadIdx.x], tot);
    }
}

// ---------- K5: horizontal 11-tap box sum on mask ----------
__global__ void k_blurh(float* __restrict__ ws) {
    int i = blockIdx.x*blockDim.x + threadIdx.x;  // NPX
    int x = i & 255;
    const float* m = ws + MASK_OFF;
    float s = 0.f;
    #pragma unroll
    for (int d = -5; d <= 5; ++d) {
        int xx = x + d;
        if (xx >= 0 && xx < 256) s += m[i - x + xx];
    }
    ws[TMP_OFF + i] = s;
}

// ---------- K6: vertical blur + window-boost accumulation -> partials ----------
__global__ void k_win(const float* __restrict__ pred, const float* __restrict__ targ,
                      float* __restrict__ ws) {
    int i = blockIdx.x*blockDim.x + threadIdx.x;
    int b = i >> 16, hw = i & 65535, y = hw >> 8;
    const float* tm = ws + TMP_OFF + b*HW;
    float s = 0.f;
    #pragma unroll
    for (int d = -5; d <= 5; ++d) {
        int yy = y + d;
        if (yy >= 0 && yy < 256) s += tm[hw + d*256];
    }
    float m = s * (1.f/121.f);
    const float* p = pred + b*3*HW + hw;
    const float* t = targ + b*3*HW + hw;
    float pr = p[0], pg = p[HW], pb = p[2*HW];
    float tr = t[0], tg = t[HW], tb = t[2*HW];
    float e3 = fabsf(pr-tr) + fabsf(pg-tg) + fabsf(pb-tb);
    float tmx = fmaxf(tr, fmaxf(tg, tb)), tmn = fminf(tr, fminf(tg, tb));
    float tsat = (tmx - tmn + 1e-7f) / (tmx + 1e-7f);
    float pmx = fmaxf(pr, fmaxf(pg, pb)), pmn = fminf(pr, fminf(pg, pb));
    float psat = (pmx - pmn + 1e-7f) / (pmx + 1e-7f);
    float sd = fabsf(psat - tsat);
    __shared__ float sb[8];
    float v;
    v = blockSum(e3*m, sb); if (threadIdx.x == 0) ws[P_WIN + blockIdx.x] = v;
    v = blockSum(sd*m, sb); if (threadIdx.x == 0) ws[P_WIN + 2048 + blockIdx.x] = v;
    v = blockSum(m,    sb); if (threadIdx.x == 0) ws[P_WIN + 4096 + blockIdx.x] = v;
}

// ---------- K7: row FFT (real input -> 129 bins) ----------
__global__ __launch_bounds__(64) void k_fft_row(const float* __restrict__ pred,
                                                const float* __restrict__ targ,
                                                float* __restrict__ ws) {
    int bid = blockIdx.x;          // 48*256
    int s = bid >> 8, r = bid & 255;
    const float* src = (s < 24 ? pred + s*HW : targ + (s-24)*HW) + r*256;
    float2* out = (float2*)(ws + (s < 24 ? FFT_P + s*66048 : FFT_T + (s-24)*66048)) + r*129;
    __shared__ float2 a[256];
    int tid = threadIdx.x;
    #pragma unroll
    for (int j = 0; j < 4; ++j) {
        int i = tid + 64*j;
        a[__brev((unsigned)i) >> 24] = make_float2(src[i], 0.f);
    }
    __syncthreads();
    #pragma unroll
    for (int st = 0; st < 8; ++st) {
        int half = 1 << st, m = half << 1;
        #pragma unroll
        for (int k = 0; k < 2; ++k) {
            int bb = tid + 64*k;
            int j = bb & (half - 1);
            int i0 = ((bb >> st) << (st + 1)) + j;
            int i1 = i0 + half;
            float ang = -6.283185307f * (float)j / (float)m;
            float si, co;
            __sincosf(ang, &si, &co);
            float2 u = a[i0], v = a[i1];
            float2 w = make_float2(v.x*co - v.y*si, v.x*si + v.y*co);
            a[i0] = make_float2(u.x + w.x, u.y + w.y);
            a[i1] = make_float2(u.x - w.x, u.y - w.y);
        }
        __syncthreads();
    }
    out[tid] = a[tid];
    out[tid + 64] = a[tid + 64];
    if (tid == 0) out[128] = a[128];
}

// ---------- K8: column FFT, 8 columns x {P,T} per block -> partials ----------
__global__ __launch_bounds__(256) void k_fft_col(float* __restrict__ ws) {
    int bid = blockIdx.x;          // 24*17 = 408
    int s = bid / 17, kt = bid - s*17;
    int k0 = kt * 8;
    __shared__ float2 arr[16][257];   // [fid][elem], odd pad breaks conflicts
    __shared__ float sb[8];
    int tid = threadIdx.x;
    const float2* srcP = (const float2*)(ws + FFT_P) + s*33024;
    const float2* srcT = (const float2*)(ws + FFT_T) + s*33024;
    int kk = tid & 7, r0 = tid >> 3;          // r0: 0..31
    int col = k0 + kk;
    bool valid = (col <= 128);
    #pragma unroll
    for (int rb = 0; rb < 8; ++rb) {
        int r = r0 + rb*32;
        int br = __brev((unsigned)r) >> 24;
        float2 vp = valid ? srcP[r*129 + col] : make_float2(0.f, 0.f);
        arr[kk][br] = vp;
        float2 vt = valid ? srcT[r*129 + col] : make_float2(0.f, 0.f);
        arr[8 + kk][br] = vt;
    }
    __syncthreads();
    int fid = tid >> 4, w = tid & 15;
    float2* a = arr[fid];
    #pragma unroll
    for (int st = 0; st < 8; ++st) {
        int half = 1 << st, m = half << 1;
        #pragma unroll
        for (int q = 0; q < 8; ++q) {
            int b = w + (q << 4);       // 0..127
            int j = b & (half - 1);
            int i0 = ((b >> st) << (st + 1)) + j;
            int i1 = i0 + half;
            float ang = -6.283185307f * (float)j / (float)m;
            float si, co;
            __sincosf(ang, &si, &co);
            float2 u = a[i0], v = a[i1];
            float2 wv = make_float2(v.x*co - v.y*si, v.x*si + v.y*co);
            a[i0] = make_float2(u.x + wv.x, u.y + wv.y);
            a[i1] = make_float2(u.x - wv.x, u.y - wv.y);
        }
        __syncthreads();
    }
    float d1 = 0.f, d2 = 0.f;
    #pragma unroll
    for (int e = 0; e < 8; ++e) {
        int idx = tid + e*256;            // < 2048
        int k = idx >> 8, r = idx & 255;
        if (k0 + k <= 128) {
            float2 zp = arr[k][r], zt = arr[8 + k][r];
            float mp = sqrtf(zp.x*zp.x + zp.y*zp.y);
            float mt = sqrtf(zt.x*zt.x + zt.y*zt.y);
            float d = fabsf(mt - mp) * (1.f/256.f);
            d1 += d; d2 += d*d;
        }
    }
    float v;
    v = blockSum(d1, sb); if (tid == 0) ws[P_FFT + bid] = v;
    v = blockSum(d2, sb); if (tid == 0) ws[P_FFT + 408 + bid] = v;
}

// ---------- K9: final assembly (reduces all partials) ----------
__global__ __launch_bounds__(256) void k_final(const float* __restrict__ ws,
                                               float* __restrict__ out) {
    __shared__ float red[256];
    __shared__ float sb[8];
    int tid = threadIdx.x;
    // ---- partial reductions ----
    float a0=0.f, a1=0.f, a2=0.f;
    for (int i = tid; i < 2048; i += 256) {
        a0 += ws[P_POINT + i];
        a1 += ws[P_POINT + 2048 + i];
        a2 += ws[P_POINT + 4096 + i];
    }
    float w0=0.f, w1=0.f, w2=0.f;
    for (int i = tid; i < 2048; i += 256) {
        w0 += ws[P_WIN + i];
        w1 += ws[P_WIN + 2048 + i];
        w2 += ws[P_WIN + 4096 + i];
    }
    float m0=0.f, m1=0.f;
    for (int i = tid; i < 384; i += 256) {
        m0 += ws[P_MS + i];
        m1 += ws[P_MS + 384 + i];
    }
    float f0=0.f, f1=0.f;
    for (int i = tid; i < 408; i += 256) {
        f0 += ws[P_FFT + i];
        f1 += ws[P_FFT + 408 + i];
    }
    float sum_e3 = blockSum(a0, sb);
    float sum_L  = blockSum(a1, sb);
    float sum_ab = blockSum(a2, sb);
    float wnum   = blockSum(w0, sb);
    float wsat   = blockSum(w1, sb);
    float wm     = blockSum(w2, sb);
    float S2     = blockSum(m0, sb);
    float S4     = blockSum(m1, sb);
    float d1     = blockSum(f0, sb);
    float d2     = blockSum(f1, sb);
    // ---- curve ----
    float cv = 0.f;
    if (tid < 96) {
        float cnt = ws[CURVE_CNT + tid];
        if (cnt > 0.f) cv = fabsf(ws[CURVE_PS + tid] - ws[CURVE_TS + tid]) / cnt;
    }
    red[tid] = cv;
    __syncthreads();
    for (int o = 128; o > 0; o >>= 1) { if (tid < o) red[tid] += red[tid + o]; __syncthreads(); }
    float curve = red[0] / 96.f;
    __syncthreads();
    // ---- histogram EMD ----
    float hacc = 0.f;
    if (tid < 24) {
        const float* hp = ws + HIST_OFF + tid*64;
        const float* ht = ws + HIST_OFF + (24 + tid)*64;
        float sp = 0.f, stt = 0.f;
        for (int k = 0; k < 64; ++k) { sp += hp[k]; stt += ht[k]; }
        float ip = 1.f / (sp + 1e-7f), it = 1.f / (stt + 1e-7f);
        float cp = 0.f, ct = 0.f;
        for (int k = 0; k < 64; ++k) {
            cp += hp[k] * ip;
            ct += ht[k] * it;
            hacc += fabsf(cp - ct);
        }
    }
    red[tid] = hacc;
    __syncthreads();
    for (int o = 128; o > 0; o >>= 1) { if (tid < o) red[tid] += red[tid + o]; __syncthreads(); }
    float hl = red[0] / 1536.f;
    if (tid == 0) {
        float l1  = sum_e3 / (float)NEL;
        float lab = (sum_L / (float)NPX) * 0.01f + 2.f * (sum_ab / (2.f * (float)NPX * 128.f));
        float ms  = (l1 + S2 / 393216.f + S4 / 98304.f) * (1.f/3.f);
        const float M = 792576.f;
        float ff  = (d2 / M) / (d1 / M + 1e-8f);
        float wb  = wnum / (wm*3.f + 1e-7f) + 0.5f * (wsat / (wm + 1e-7f));
        out[0] = l1 + 0.3f*ff + 0.4f*lab + 0.3f*ms + 0.4f*curve + 0.2f*hl + 0.5f*wb;
    }
}

extern "C" void kernel_launch(void* const* d_in, const int* in_sizes, int n_in,
                              void* d_out, int out_size, void* d_ws, size_t ws_size,
                              hipStream_t stream) {
    const float* pred = (const float*)d_in[0];
    const float* targ = (const float*)d_in[1];
    const float* inp  = (const float*)d_in[2];
    float* ws = (float*)d_ws;
    float* out = (float*)d_out;

    hipMemsetAsync(d_ws, 0, ZERO_FLOATS * sizeof(float), stream);

    // mask pipeline first (its scratch is overwritten by the FFT buffers)
    k_point  <<<2048, 256, 0, stream>>>(pred, targ, ws);
    k_blurh  <<<2048, 256, 0, stream>>>(ws);
    k_win    <<<2048, 256, 0, stream>>>(pred, targ, ws);
    // independent reductions
    k_ms     <<<384,  256, 0, stream>>>(pred, targ, ws);
    k_curve  <<<192,  256, 0, stream>>>(pred, targ, inp, ws);
    k_hist   <<<768,  256, 0, stream>>>(pred, targ, ws);
    // FFT (reuses mask/tmp scratch region)
    k_fft_row<<<12288, 64, 0, stream>>>(pred, targ, ws);
    k_fft_col<<<408,  256, 0, stream>>>(ws);
    k_final  <<<1,    256, 0, stream>>>(ws, out);
}

// Round 9
// 103.741 us; speedup vs baseline: 3.6382x; 1.2019x over previous
//
#include <hip/hip_runtime.h>
#include <math.h>

#define HW 65536
#define NPX 524288      // 8*256*256
#define NEL 1572864     // 8*3*256*256

// ---- ws layout (float offsets) ----
// per-block partial arrays (no atomics; every slot written each call; no zeroing needed)
#define P_POINT   4096                  // 3 x 2048  -> ends 10240
#define P_MS      10240                 // 2 x 384   -> ends 11008
#define P_WIN     11008                 // 3 x 2048  -> ends 17152
#define P_FFT     17152                 // 2 x 408   -> ends 17968
#define P_CURVE   17968                 // 192 x 96  -> ends 36400
#define P_HIST    36400                 // 768 x 64  -> ends 85552
// mask/blur scratch (used first, then overwritten by FFT buffers)
#define MASK_OFF  86016
#define TMP_OFF   (86016 + 524288)
// FFT buffers OVERLAP mask/tmp (stream ordering: mask pipeline done first)
#define FFT_P     86016                 // 24 slices * 66048 floats
#define FFT_T     (FFT_P + 24*66048)
// total floats = FFT_T + 24*66048 = 3,256,320  (~13.0 MB)

#define CURVE_SCALE 131072.0f     // 2^17 fixed-point
#define HIST_SCALE  131072.0f     // weights<=1, <=4096/bin/block -> <=2^29 < u32

// ---------- fast transcendentals (args strictly positive on use) ----------
__device__ __forceinline__ float fpow24(float x) {     // x^2.4, x > 0.04045
    return __builtin_amdgcn_exp2f(2.4f * __builtin_amdgcn_logf(x));
}
__device__ __forceinline__ float fcbrt(float x) {      // x^(1/3), x > 0.0088
    return __builtin_amdgcn_exp2f((1.0f/3.0f) * __builtin_amdgcn_logf(x));
}

// ---------- helpers ----------
__device__ __forceinline__ float labF(float t) {
    return t > 0.008856452f ? fcbrt(t) : t * 7.787037f + 0.13793103f;
}

__device__ __forceinline__ void rgb2lab(float r, float g, float b,
                                        float& L, float& A, float& Bc) {
    float lr = r > 0.04045f ? fpow24((r + 0.055f) * (1.0f/1.055f)) : r * (1.0f/12.92f);
    float lg = g > 0.04045f ? fpow24((g + 0.055f) * (1.0f/1.055f)) : g * (1.0f/12.92f);
    float lb = b > 0.04045f ? fpow24((b + 0.055f) * (1.0f/1.055f)) : b * (1.0f/12.92f);
    float X = (0.4124564f*lr + 0.3575761f*lg + 0.1804375f*lb) * (1.0f/0.95047f);
    float Y = (0.2126729f*lr + 0.7151522f*lg + 0.0721750f*lb);
    float Z = (0.0193339f*lr + 0.1191920f*lg + 0.9503041f*lb) * (1.0f/1.08883f);
    float fx = labF(X), fy = labF(Y), fz = labF(Z);
    L = 116.f*fy - 16.f;
    A = 500.f*(fx - fy);
    Bc = 200.f*(fy - fz);
}

// block-wide sum; returns total on thread 0 (0 elsewhere); ends with barrier
__device__ __forceinline__ float blockSum(float v, float* sb) {
    #pragma unroll
    for (int o = 32; o > 0; o >>= 1) v += __shfl_down(v, o, 64);
    int lane = threadIdx.x & 63, w = threadIdx.x >> 6;
    if (lane == 0) sb[w] = v;
    __syncthreads();
    float r = 0.f;
    if (threadIdx.x == 0) {
        int nw = (blockDim.x + 63) >> 6;
        for (int i = 0; i < nw; ++i) r += sb[i];
    }
    __syncthreads();
    return r;
}

// ---------- K1: pointwise (L1, LAB, target mask) -> per-block partials ----------
__global__ void k_point(const float* __restrict__ pred, const float* __restrict__ targ,
                        float* __restrict__ ws) {
    int i = blockIdx.x * blockDim.x + threadIdx.x;   // < NPX
    int b = i >> 16, hw = i & 65535;
    const float* p = pred + b*3*HW + hw;
    const float* t = targ + b*3*HW + hw;
    float pr = p[0], pg = p[HW], pb = p[2*HW];
    float tr = t[0], tg = t[HW], tb = t[2*HW];
    float e3 = fabsf(pr-tr) + fabsf(pg-tg) + fabsf(pb-tb);
    float Lp,Ap,Bp, Lt,At,Bt;
    rgb2lab(pr,pg,pb, Lp,Ap,Bp);
    rgb2lab(tr,tg,tb, Lt,At,Bt);
    float sL = fabsf(Lp-Lt);
    float sab = fabsf(Ap-At) + fabsf(Bp-Bt);
    float tmx = fmaxf(tr, fmaxf(tg, tb)), tmn = fminf(tr, fminf(tg, tb));
    float tsat = (tmx - tmn + 1e-7f) / (tmx + 1e-7f);
    ws[MASK_OFF + i] = (tmx > 0.6f && tsat > 0.2f) ? 1.f : 0.f;
    __shared__ float sb[8];
    float v;
    v = blockSum(e3, sb);  if (threadIdx.x == 0) ws[P_POINT + blockIdx.x] = v;
    v = blockSum(sL, sb);  if (threadIdx.x == 0) ws[P_POINT + 2048 + blockIdx.x] = v;
    v = blockSum(sab, sb); if (threadIdx.x == 0) ws[P_POINT + 4096 + blockIdx.x] = v;
}

// ---------- K2: multi-scale pooled L1 -> partials ----------
__global__ void k_ms(const float* __restrict__ pred, const float* __restrict__ targ,
                     float* __restrict__ ws) {
    int t = blockIdx.x * blockDim.x + threadIdx.x;   // < 98304
    int sc = t >> 12;              // (b,c) slice 0..23
    int q = t & 4095;
    int y4 = q >> 6, x4 = q & 63;
    const float* pp = pred + sc*HW + (y4*4)*256 + x4*4;
    const float* tp = targ + sc*HW + (y4*4)*256 + x4*4;
    float4 p0 = *(const float4*)(pp);
    float4 p1 = *(const float4*)(pp + 256);
    float4 p2 = *(const float4*)(pp + 512);
    float4 p3 = *(const float4*)(pp + 768);
    float4 q0 = *(const float4*)(tp);
    float4 q1 = *(const float4*)(tp + 256);
    float4 q2 = *(const float4*)(tp + 512);
    float4 q3 = *(const float4*)(tp + 768);
    float a00 = (p0.x+p0.y+p1.x+p1.y)*0.25f, a01 = (p0.z+p0.w+p1.z+p1.w)*0.25f;
    float a10 = (p2.x+p2.y+p3.x+p3.y)*0.25f, a11 = (p2.z+p2.w+p3.z+p3.w)*0.25f;
    float b00 = (q0.x+q0.y+q1.x+q1.y)*0.25f, b01 = (q0.z+q0.w+q1.z+q1.w)*0.25f;
    float b10 = (q2.x+q2.y+q3.x+q3.y)*0.25f, b11 = (q2.z+q2.w+q3.z+q3.w)*0.25f;
    float s2 = fabsf(a00-b00)+fabsf(a01-b01)+fabsf(a10-b10)+fabsf(a11-b11);
    float s4 = fabsf((a00+a01+a10+a11)*0.25f - (b00+b01+b10+b11)*0.25f);
    __shared__ float sb[8];
    float v;
    v = blockSum(s2, sb); if (threadIdx.x == 0) ws[P_MS + blockIdx.x] = v;
    v = blockSum(s4, sb); if (threadIdx.x == 0) ws[P_MS + 384 + blockIdx.x] = v;
}

// ---------- K3: color-curve segment sums (u32 LDS atomics) -> per-block partials ----------
// 192 blocks: block = (slice 0..23) * 8 + part; each handles 8192 contiguous elems
__global__ __launch_bounds__(256) void k_curve(const float* __restrict__ pred,
                                               const float* __restrict__ targ,
                                               const float* __restrict__ inp,
                                               float* __restrict__ ws) {
    __shared__ unsigned h[288];            // [seg*3 + {cnt,ps,ts}]
    int tid = threadIdx.x;
    if (tid < 256) h[tid] = 0u;
    if (tid < 32) h[256 + tid] = 0u;
    __syncthreads();
    int blk = blockIdx.x;
    int slice = blk >> 3, part = blk & 7;
    int c = slice % 3;
    int base = slice * HW + part * 8192;
    const float4* ip = (const float4*)(inp + base);
    const float4* pp = (const float4*)(pred + base);
    const float4* tp = (const float4*)(targ + base);
    int segbase = 32 * c;
    #pragma unroll
    for (int it = 0; it < 8; ++it) {
        float4 a = ip[it*256 + tid];
        float4 p = pp[it*256 + tid];
        float4 t = tp[it*256 + tid];
        float av[4] = {a.x, a.y, a.z, a.w};
        float pv[4] = {p.x, p.y, p.z, p.w};
        float tv[4] = {t.x, t.y, t.z, t.w};
        #pragma unroll
        for (int j = 0; j < 4; ++j) {
            int idx = (int)(av[j] * 32.f);
            idx = min(max(idx, 0), 31);
            unsigned s3 = (unsigned)((segbase + idx) * 3);
            atomicAdd(&h[s3],     1u);
            atomicAdd(&h[s3 + 1], (unsigned)__float2uint_rn(pv[j] * CURVE_SCALE));
            atomicAdd(&h[s3 + 2], (unsigned)__float2uint_rn(tv[j] * CURVE_SCALE));
        }
    }
    __syncthreads();
    // write this block's 32 active bins x {cnt,ps,ts} (channel-local layout)
    if (tid < 96) {
        unsigned v = h[segbase*3 + tid];
        int q = tid - (tid/3)*3;
        float f = (q == 0) ? (float)v : (float)v * (1.f/CURVE_SCALE);
        ws[P_CURVE + blk*96 + tid] = f;
    }
}

// ---------- K4: soft histogram, element-major +-6 window -> per-block partials ----------
// 768 blocks = 48 slices x 16 parts; 4096 elems per block
__global__ __launch_bounds__(256) void k_hist(const float* __restrict__ pred,
                                              const float* __restrict__ targ,
                                              float* __restrict__ ws) {
    int blk = blockIdx.x;
    int s = blk >> 4, part = blk & 15;
    const float* src = (s < 24 ? pred + s*HW : targ + (s-24)*HW) + part*4096;
    __shared__ unsigned hb[4][64];         // per-wave sub-histograms
    int tid = threadIdx.x, wv = tid >> 6, ln = tid & 63;
    hb[wv][ln] = 0u;
    __syncthreads();
    const float4* s4 = (const float4*)src;
    #pragma unroll
    for (int it = 0; it < 4; ++it) {
        float4 v = s4[it*256 + tid];
        float vals[4] = {v.x, v.y, v.z, v.w};
        #pragma unroll
        for (int e = 0; e < 4; ++e) {
            float t = vals[e] * 63.f;
            int k0 = (int)floorf(t) - 6;
            #pragma unroll
            for (int j = 0; j < 13; ++j) {
                int k = k0 + j;
                float u = t - (float)k;
                // exp(-(x-c)^2/(2 bw^2)) = exp2(-0.7445747 * u^2), u in center-spacing units
                float w = __builtin_amdgcn_exp2f(-0.7445747f * u * u);
                if (k >= 0 && k < 64)
                    atomicAdd(&hb[wv][k], (unsigned)__float2uint_rn(w * HIST_SCALE));
            }
        }
    }
    __syncthreads();
    if (tid < 64) {
        float tot = (float)(hb[0][tid] + hb[1][tid] + hb[2][tid] + hb[3][tid]) * (1.f/HIST_SCALE);
        ws[P_HIST + blk*64 + tid] = tot;
    }
}

// ---------- K5: horizontal 11-tap box sum on mask ----------
__global__ void k_blurh(float* __restrict__ ws) {
    int i = blockIdx.x*blockDim.x + threadIdx.x;  // NPX
    int x = i & 255;
    const float* m = ws + MASK_OFF;
    float s = 0.f;
    #pragma unroll
    for (int d = -5; d <= 5; ++d) {
        int xx = x + d;
        if (xx >= 0 && xx < 256) s += m[i - x + xx];
    }
    ws[TMP_OFF + i] = s;
}

// ---------- K6: vertical blur + window-boost accumulation -> partials ----------
__global__ void k_win(const float* __restrict__ pred, const float* __restrict__ targ,
                      float* __restrict__ ws) {
    int i = blockIdx.x*blockDim.x + threadIdx.x;
    int b = i >> 16, hw = i & 65535, y = hw >> 8;
    const float* tm = ws + TMP_OFF + b*HW;
    float s = 0.f;
    #pragma unroll
    for (int d = -5; d <= 5; ++d) {
        int yy = y + d;
        if (yy >= 0 && yy < 256) s += tm[hw + d*256];
    }
    float m = s * (1.f/121.f);
    const float* p = pred + b*3*HW + hw;
    const float* t = targ + b*3*HW + hw;
    float pr = p[0], pg = p[HW], pb = p[2*HW];
    float tr = t[0], tg = t[HW], tb = t[2*HW];
    float e3 = fabsf(pr-tr) + fabsf(pg-tg) + fabsf(pb-tb);
    float tmx = fmaxf(tr, fmaxf(tg, tb)), tmn = fminf(tr, fminf(tg, tb));
    float tsat = (tmx - tmn + 1e-7f) / (tmx + 1e-7f);
    float pmx = fmaxf(pr, fmaxf(pg, pb)), pmn = fminf(pr, fminf(pg, pb));
    float psat = (pmx - pmn + 1e-7f) / (pmx + 1e-7f);
    float sd = fabsf(psat - tsat);
    __shared__ float sb[8];
    float v;
    v = blockSum(e3*m, sb); if (threadIdx.x == 0) ws[P_WIN + blockIdx.x] = v;
    v = blockSum(sd*m, sb); if (threadIdx.x == 0) ws[P_WIN + 2048 + blockIdx.x] = v;
    v = blockSum(m,    sb); if (threadIdx.x == 0) ws[P_WIN + 4096 + blockIdx.x] = v;
}

// ---------- K7: row FFT (real input -> 129 bins) ----------
__global__ __launch_bounds__(64) void k_fft_row(const float* __restrict__ pred,
                                                const float* __restrict__ targ,
                                                float* __restrict__ ws) {
    int bid = blockIdx.x;          // 48*256
    int s = bid >> 8, r = bid & 255;
    const float* src = (s < 24 ? pred + s*HW : targ + (s-24)*HW) + r*256;
    float2* out = (float2*)(ws + (s < 24 ? FFT_P + s*66048 : FFT_T + (s-24)*66048)) + r*129;
    __shared__ float2 a[256];
    int tid = threadIdx.x;
    #pragma unroll
    for (int j = 0; j < 4; ++j) {
        int i = tid + 64*j;
        a[__brev((unsigned)i) >> 24] = make_float2(src[i], 0.f);
    }
    __syncthreads();
    #pragma unroll
    for (int st = 0; st < 8; ++st) {
        int half = 1 << st, m = half << 1;
        #pragma unroll
        for (int k = 0; k < 2; ++k) {
            int bb = tid + 64*k;
            int j = bb & (half - 1);
            int i0 = ((bb >> st) << (st + 1)) + j;
            int i1 = i0 + half;
            float ang = -6.283185307f * (float)j / (float)m;
            float si, co;
            __sincosf(ang, &si, &co);
            float2 u = a[i0], v = a[i1];
            float2 w = make_float2(v.x*co - v.y*si, v.x*si + v.y*co);
            a[i0] = make_float2(u.x + w.x, u.y + w.y);
            a[i1] = make_float2(u.x - w.x, u.y - w.y);
        }
        __syncthreads();
    }
    out[tid] = a[tid];
    out[tid + 64] = a[tid + 64];
    if (tid == 0) out[128] = a[128];
}

// ---------- K8: column FFT, 8 columns x {P,T} per block -> partials ----------
__global__ __launch_bounds__(256) void k_fft_col(float* __restrict__ ws) {
    int bid = blockIdx.x;          // 24*17 = 408
    int s = bid / 17, kt = bid - s*17;
    int k0 = kt * 8;
    __shared__ float2 arr[16][257];   // [fid][elem], odd pad breaks conflicts
    __shared__ float sb[8];
    int tid = threadIdx.x;
    const float2* srcP = (const float2*)(ws + FFT_P) + s*33024;
    const float2* srcT = (const float2*)(ws + FFT_T) + s*33024;
    int kk = tid & 7, r0 = tid >> 3;          // r0: 0..31
    int col = k0 + kk;
    bool valid = (col <= 128);
    #pragma unroll
    for (int rb = 0; rb < 8; ++rb) {
        int r = r0 + rb*32;
        int br = __brev((unsigned)r) >> 24;
        float2 vp = valid ? srcP[r*129 + col] : make_float2(0.f, 0.f);
        arr[kk][br] = vp;
        float2 vt = valid ? srcT[r*129 + col] : make_float2(0.f, 0.f);
        arr[8 + kk][br] = vt;
    }
    __syncthreads();
    int fid = tid >> 4, w = tid & 15;
    float2* a = arr[fid];
    #pragma unroll
    for (int st = 0; st < 8; ++st) {
        int half = 1 << st, m = half << 1;
        #pragma unroll
        for (int q = 0; q < 8; ++q) {
            int b = w + (q << 4);       // 0..127
            int j = b & (half - 1);
            int i0 = ((b >> st) << (st + 1)) + j;
            int i1 = i0 + half;
            float ang = -6.283185307f * (float)j / (float)m;
            float si, co;
            __sincosf(ang, &si, &co);
            float2 u = a[i0], v = a[i1];
            float2 wv = make_float2(v.x*co - v.y*si, v.x*si + v.y*co);
            a[i0] = make_float2(u.x + wv.x, u.y + wv.y);
            a[i1] = make_float2(u.x - wv.x, u.y - wv.y);
        }
        __syncthreads();
    }
    float d1 = 0.f, d2 = 0.f;
    #pragma unroll
    for (int e = 0; e < 8; ++e) {
        int idx = tid + e*256;            // < 2048
        int k = idx >> 8, r = idx & 255;
        if (k0 + k <= 128) {
            float2 zp = arr[k][r], zt = arr[8 + k][r];
            float mp = sqrtf(zp.x*zp.x + zp.y*zp.y);
            float mt = sqrtf(zt.x*zt.x + zt.y*zt.y);
            float d = fabsf(mt - mp) * (1.f/256.f);
            d1 += d; d2 += d*d;
        }
    }
    float v;
    v = blockSum(d1, sb); if (tid == 0) ws[P_FFT + bid] = v;
    v = blockSum(d2, sb); if (tid == 0) ws[P_FFT + 408 + bid] = v;
}

// ---------- K9: final assembly (reduces all partials) ----------
__global__ __launch_bounds__(256) void k_final(const float* __restrict__ ws,
                                               float* __restrict__ out) {
    __shared__ float shist[3072];
    __shared__ float red[256];
    __shared__ float sb[8];
    int tid = threadIdx.x;
    // ---- pre-reduce hist parts (16 per slice-bin), coalesced ----
    for (int q = tid; q < 3072; q += 256) {
        int s = q >> 6, k = q & 63;
        float t = 0.f;
        const float* base = ws + P_HIST + s*16*64 + k;
        #pragma unroll
        for (int p = 0; p < 16; ++p) t += base[p*64];
        shist[q] = t;
    }
    // ---- scalar partial reductions ----
    float a0=0.f, a1=0.f, a2=0.f;
    for (int i = tid; i < 2048; i += 256) {
        a0 += ws[P_POINT + i];
        a1 += ws[P_POINT + 2048 + i];
        a2 += ws[P_POINT + 4096 + i];
    }
    float w0=0.f, w1=0.f, w2=0.f;
    for (int i = tid; i < 2048; i += 256) {
        w0 += ws[P_WIN + i];
        w1 += ws[P_WIN + 2048 + i];
        w2 += ws[P_WIN + 4096 + i];
    }
    float m0=0.f, m1=0.f;
    for (int i = tid; i < 384; i += 256) {
        m0 += ws[P_MS + i];
        m1 += ws[P_MS + 384 + i];
    }
    float f0=0.f, f1=0.f;
    for (int i = tid; i < 408; i += 256) {
        f0 += ws[P_FFT + i];
        f1 += ws[P_FFT + 408 + i];
    }
    float sum_e3 = blockSum(a0, sb);
    float sum_L  = blockSum(a1, sb);
    float sum_ab = blockSum(a2, sb);
    float wnum   = blockSum(w0, sb);
    float wsat   = blockSum(w1, sb);
    float wm     = blockSum(w2, sb);
    float S2     = blockSum(m0, sb);
    float S4     = blockSum(m1, sb);
    float d1     = blockSum(f0, sb);
    float d2     = blockSum(f1, sb);
    __syncthreads();
    // ---- curve: reduce per-block partials ----
    float cv = 0.f;
    if (tid < 96) {
        int c = tid >> 5, i = tid & 31;
        float cnt=0.f, ps=0.f, ts=0.f;
        for (int ss = c; ss < 24; ss += 3) {
            for (int p = 0; p < 8; ++p) {
                const float* base = ws + P_CURVE + ((ss<<3) + p)*96 + i*3;
                cnt += base[0]; ps += base[1]; ts += base[2];
            }
        }
        if (cnt > 0.f) cv = fabsf(ps - ts) / cnt;
    }
    red[tid] = cv;
    __syncthreads();
    for (int o = 128; o > 0; o >>= 1) { if (tid < o) red[tid] += red[tid + o]; __syncthreads(); }
    float curve = red[0] / 96.f;
    __syncthreads();
    // ---- histogram EMD from shist ----
    float hacc = 0.f;
    if (tid < 24) {
        const float* hp = shist + tid*64;
        const float* ht = shist + (24 + tid)*64;
        float sp = 0.f, stt = 0.f;
        for (int k = 0; k < 64; ++k) { sp += hp[k]; stt += ht[k]; }
        float ip = 1.f / (sp + 1e-7f), it = 1.f / (stt + 1e-7f);
        float cp = 0.f, ct = 0.f;
        for (int k = 0; k < 64; ++k) {
            cp += hp[k] * ip;
            ct += ht[k] * it;
            hacc += fabsf(cp - ct);
        }
    }
    red[tid] = hacc;
    __syncthreads();
    for (int o = 128; o > 0; o >>= 1) { if (tid < o) red[tid] += red[tid + o]; __syncthreads(); }
    float hl = red[0] / 1536.f;
    if (tid == 0) {
        float l1  = sum_e3 / (float)NEL;
        float lab = (sum_L / (float)NPX) * 0.01f + 2.f * (sum_ab / (2.f * (float)NPX * 128.f));
        float ms  = (l1 + S2 / 393216.f + S4 / 98304.f) * (1.f/3.f);
        const float M = 792576.f;
        float ff  = (d2 / M) / (d1 / M + 1e-8f);
        float wb  = wnum / (wm*3.f + 1e-7f) + 0.5f * (wsat / (wm + 1e-7f));
        out[0] = l1 + 0.3f*ff + 0.4f*lab + 0.3f*ms + 0.4f*curve + 0.2f*hl + 0.5f*wb;
    }
}

extern "C" void kernel_launch(void* const* d_in, const int* in_sizes, int n_in,
                              void* d_out, int out_size, void* d_ws, size_t ws_size,
                              hipStream_t stream) {
    const float* pred = (const float*)d_in[0];
    const float* targ = (const float*)d_in[1];
    const float* inp  = (const float*)d_in[2];
    float* ws = (float*)d_ws;
    float* out = (float*)d_out;

    // mask pipeline first (its scratch is overwritten by the FFT buffers)
    k_point  <<<2048, 256, 0, stream>>>(pred, targ, ws);
    k_blurh  <<<2048, 256, 0, stream>>>(ws);
    k_win    <<<2048, 256, 0, stream>>>(pred, targ, ws);
    // independent reductions (all write partials; no zeroing required)
    k_ms     <<<384,  256, 0, stream>>>(pred, targ, ws);
    k_curve  <<<192,  256, 0, stream>>>(pred, targ, inp, ws);
    k_hist   <<<768,  256, 0, stream>>>(pred, targ, ws);
    // FFT (reuses mask/tmp scratch region)
    k_fft_row<<<12288, 64, 0, stream>>>(pred, targ, ws);
    k_fft_col<<<408,  256, 0, stream>>>(ws);
    k_final  <<<1,    256, 0, stream>>>(ws, out);
}

// Round 10
// 69.285 us; speedup vs baseline: 5.4475x; 1.4973x over previous
//
#include <hip/hip_runtime.h>
#include <math.h>

#define HW 65536
#define NPX 524288      // 8*256*256
#define NEL 1572864     // 8*3*256*256

// ---- ws layout (float offsets); ws_size ~268MB, we use ~15MB ----
// per-block partial arrays (no atomics; every slot written every call)
#define P_POINT 4096      // 3 x 2048  -> 10240
#define P_MS    10240     // 2 x 384   -> 11008
#define P_WIN   11008     // 3 x 512   -> 12544
#define P_FFT   12544     // 2 x 408   -> 13360
#define P_CURVE 13360     // 192 x 96  -> 31792
#define P_HIST  31792     // 384 x 64  -> 56368
#define MASK_OFF 65536    // 524288 floats
#define FFT_P   589824    // 24 slices * 66048 floats
#define FFT_T   (FFT_P + 24*66048)
// total ~3.76M floats (~15 MB)

#define CURVE_SCALE 131072.0f

// MEGA1 block roles
#define B_POINT 2048
#define B_MS    384
#define B_CURVE 192
#define B_HIST  384
#define B_FFTR  3072          // 4 row-FFTs per block
#define G_MEGA1 (B_POINT+B_MS+B_CURVE+B_HIST+B_FFTR)   // 6080
// MEGA2 block roles
#define B_WIN   512           // 4-row strips (8 batches x 64 strips)
#define B_FFTC  408
#define G_MEGA2 (B_WIN+B_FFTC)                          // 920

// ---------- fast transcendentals (args strictly positive on use) ----------
__device__ __forceinline__ float fpow24(float x) {
    return __builtin_amdgcn_exp2f(2.4f * __builtin_amdgcn_logf(x));
}
__device__ __forceinline__ float fcbrt(float x) {
    return __builtin_amdgcn_exp2f((1.0f/3.0f) * __builtin_amdgcn_logf(x));
}

__device__ __forceinline__ float labF(float t) {
    return t > 0.008856452f ? fcbrt(t) : t * 7.787037f + 0.13793103f;
}

__device__ __forceinline__ void rgb2lab(float r, float g, float b,
                                        float& L, float& A, float& Bc) {
    float lr = r > 0.04045f ? fpow24((r + 0.055f) * (1.0f/1.055f)) : r * (1.0f/12.92f);
    float lg = g > 0.04045f ? fpow24((g + 0.055f) * (1.0f/1.055f)) : g * (1.0f/12.92f);
    float lb = b > 0.04045f ? fpow24((b + 0.055f) * (1.0f/1.055f)) : b * (1.0f/12.92f);
    float X = (0.4124564f*lr + 0.3575761f*lg + 0.1804375f*lb) * (1.0f/0.95047f);
    float Y = (0.2126729f*lr + 0.7151522f*lg + 0.0721750f*lb);
    float Z = (0.0193339f*lr + 0.1191920f*lg + 0.9503041f*lb) * (1.0f/1.08883f);
    float fx = labF(X), fy = labF(Y), fz = labF(Z);
    L = 116.f*fy - 16.f;
    A = 500.f*(fx - fy);
    Bc = 200.f*(fy - fz);
}

// block-wide sum; total on thread 0; ends with barrier
__device__ __forceinline__ float blockSum(float v, float* sb) {
    #pragma unroll
    for (int o = 32; o > 0; o >>= 1) v += __shfl_down(v, o, 64);
    int lane = threadIdx.x & 63, w = threadIdx.x >> 6;
    if (lane == 0) sb[w] = v;
    __syncthreads();
    float r = 0.f;
    if (threadIdx.x == 0) {
        int nw = (blockDim.x + 63) >> 6;
        for (int i = 0; i < nw; ++i) r += sb[i];
    }
    __syncthreads();
    return r;
}

// ================= MEGA1: point | ms | curve | hist | fft_row =================
__global__ __launch_bounds__(256) void k_mega1(const float* __restrict__ pred,
                                               const float* __restrict__ targ,
                                               const float* __restrict__ inp,
                                               float* __restrict__ ws) {
    __shared__ __align__(16) unsigned char sm[17408];
    int tid = threadIdx.x;
    int bid = blockIdx.x;

    if (bid < B_POINT) {
        // ---- pointwise: L1, LAB, mask ----
        float* sb = (float*)sm;
        int i = bid*256 + tid;
        int b = i >> 16, hw = i & 65535;
        const float* p = pred + b*3*HW + hw;
        const float* t = targ + b*3*HW + hw;
        float pr = p[0], pg = p[HW], pb = p[2*HW];
        float tr = t[0], tg = t[HW], tb = t[2*HW];
        float e3 = fabsf(pr-tr) + fabsf(pg-tg) + fabsf(pb-tb);
        float Lp,Ap,Bp, Lt,At,Bt;
        rgb2lab(pr,pg,pb, Lp,Ap,Bp);
        rgb2lab(tr,tg,tb, Lt,At,Bt);
        float sL = fabsf(Lp-Lt);
        float sab = fabsf(Ap-At) + fabsf(Bp-Bt);
        float tmx = fmaxf(tr, fmaxf(tg, tb)), tmn = fminf(tr, fminf(tg, tb));
        float tsat = (tmx - tmn + 1e-7f) / (tmx + 1e-7f);
        ws[MASK_OFF + i] = (tmx > 0.6f && tsat > 0.2f) ? 1.f : 0.f;
        float v;
        v = blockSum(e3, sb);  if (tid == 0) ws[P_POINT + bid] = v;
        v = blockSum(sL, sb);  if (tid == 0) ws[P_POINT + 2048 + bid] = v;
        v = blockSum(sab, sb); if (tid == 0) ws[P_POINT + 4096 + bid] = v;
    } else if (bid < B_POINT + B_MS) {
        // ---- multi-scale pooled L1 ----
        float* sb = (float*)sm;
        int blk = bid - B_POINT;
        int t = blk*256 + tid;         // < 98304
        int sc = t >> 12;
        int q = t & 4095;
        int y4 = q >> 6, x4 = q & 63;
        const float* pp = pred + sc*HW + (y4*4)*256 + x4*4;
        const float* tp = targ + sc*HW + (y4*4)*256 + x4*4;
        float4 p0 = *(const float4*)(pp);
        float4 p1 = *(const float4*)(pp + 256);
        float4 p2 = *(const float4*)(pp + 512);
        float4 p3 = *(const float4*)(pp + 768);
        float4 q0 = *(const float4*)(tp);
        float4 q1 = *(const float4*)(tp + 256);
        float4 q2 = *(const float4*)(tp + 512);
        float4 q3 = *(const float4*)(tp + 768);
        float a00 = (p0.x+p0.y+p1.x+p1.y)*0.25f, a01 = (p0.z+p0.w+p1.z+p1.w)*0.25f;
        float a10 = (p2.x+p2.y+p3.x+p3.y)*0.25f, a11 = (p2.z+p2.w+p3.z+p3.w)*0.25f;
        float b00 = (q0.x+q0.y+q1.x+q1.y)*0.25f, b01 = (q0.z+q0.w+q1.z+q1.w)*0.25f;
        float b10 = (q2.x+q2.y+q3.x+q3.y)*0.25f, b11 = (q2.z+q2.w+q3.z+q3.w)*0.25f;
        float s2 = fabsf(a00-b00)+fabsf(a01-b01)+fabsf(a10-b10)+fabsf(a11-b11);
        float s4 = fabsf((a00+a01+a10+a11)*0.25f - (b00+b01+b10+b11)*0.25f);
        float v;
        v = blockSum(s2, sb); if (tid == 0) ws[P_MS + blk] = v;
        v = blockSum(s4, sb); if (tid == 0) ws[P_MS + 384 + blk] = v;
    } else if (bid < B_POINT + B_MS + B_CURVE) {
        // ---- color-curve segment sums (u32 LDS atomics) ----
        unsigned* h = (unsigned*)sm;       // 288
        if (tid < 256) h[tid] = 0u;
        if (tid < 32) h[256 + tid] = 0u;
        __syncthreads();
        int blk = bid - (B_POINT + B_MS);  // 0..191
        int slice = blk >> 3, part = blk & 7;
        int c = slice % 3;
        int base = slice * HW + part * 8192;
        const float4* ip = (const float4*)(inp + base);
        const float4* pp = (const float4*)(pred + base);
        const float4* tp = (const float4*)(targ + base);
        int segbase = 32 * c;
        #pragma unroll
        for (int it = 0; it < 8; ++it) {
            float4 a = ip[it*256 + tid];
            float4 p = pp[it*256 + tid];
            float4 t = tp[it*256 + tid];
            float av[4] = {a.x, a.y, a.z, a.w};
            float pv[4] = {p.x, p.y, p.z, p.w};
            float tv[4] = {t.x, t.y, t.z, t.w};
            #pragma unroll
            for (int j = 0; j < 4; ++j) {
                int idx = (int)(av[j] * 32.f);
                idx = min(max(idx, 0), 31);
                unsigned s3 = (unsigned)((segbase + idx) * 3);
                atomicAdd(&h[s3],     1u);
                atomicAdd(&h[s3 + 1], (unsigned)__float2uint_rn(pv[j] * CURVE_SCALE));
                atomicAdd(&h[s3 + 2], (unsigned)__float2uint_rn(tv[j] * CURVE_SCALE));
            }
        }
        __syncthreads();
        if (tid < 96) {
            unsigned v = h[segbase*3 + tid];
            int q = tid - (tid/3)*3;
            float f = (q == 0) ? (float)v : (float)v * (1.f/CURVE_SCALE);
            ws[P_CURVE + blk*96 + tid] = f;
        }
    } else if (bid < B_POINT + B_MS + B_CURVE + B_HIST) {
        // ---- soft histogram: exact u32 fine-hist (1009 levels) + 193-tap conv ----
        unsigned (*fh)[1024] = (unsigned(*)[1024])sm;        // 4 x 1024 u32
        float* wtab = (float*)(sm + 16384);                   // 193
        int hb = bid - (B_POINT + B_MS + B_CURVE);            // 0..383
        int s = hb >> 3, part = hb & 7;
        const float* src = (s < 24 ? pred + s*HW : targ + (s-24)*HW) + part*8192;
        #pragma unroll
        for (int j = 0; j < 16; ++j) ((unsigned*)sm)[tid + 256*j] = 0u;
        if (tid < 193) {
            float d = (float)(tid - 96);
            // exp(-(x-c)^2*2048) with u=(x-c)*63 in spacings, d=16u fine units:
            // exp2(-0.744437*u^2) = exp2(-0.002907957*d^2)
            wtab[tid] = __builtin_amdgcn_exp2f(-0.002907957f * d * d);
        }
        __syncthreads();
        int wv = tid >> 6;
        const float4* s4 = (const float4*)src;
        #pragma unroll
        for (int it = 0; it < 8; ++it) {
            float4 v = s4[it*256 + tid];
            float vals[4] = {v.x, v.y, v.z, v.w};
            #pragma unroll
            for (int e = 0; e < 4; ++e) {
                unsigned f = __float2uint_rn(vals[e] * 1008.f);
                f = min(f, 1008u);
                atomicAdd(&fh[wv][f], 1u);
            }
        }
        __syncthreads();
        // merge 4 wave hists into fh[0]
        #pragma unroll
        for (int j = 0; j < 4; ++j) {
            int idx = tid + 256*j;
            fh[0][idx] = fh[0][idx] + fh[1][idx] + fh[2][idx] + fh[3][idx];
        }
        __syncthreads();
        // conv: 64 bins x 193 taps, 4 threads per bin
        int k = tid >> 2, q = tid & 3;
        float acc = 0.f;
        for (int i = q; i < 193; i += 4) {
            int f = 16*k + i - 96;
            if (f >= 0 && f <= 1008) acc += (float)fh[0][f] * wtab[i];
        }
        acc += __shfl_xor(acc, 1, 64);
        acc += __shfl_xor(acc, 2, 64);
        if (q == 0) ws[P_HIST + hb*64 + k] = acc;
    } else {
        // ---- row FFT: 4 rows per block ----
        float2 (*a4)[256] = (float2(*)[256])sm;               // 4 x 256 float2
        int fb = bid - (B_POINT + B_MS + B_CURVE + B_HIST);   // 0..3071
        int fid = tid >> 6, l = tid & 63;
        int R = fb*4 + fid;                                   // 0..12287
        int s = R >> 8, r = R & 255;
        const float* src = (s < 24 ? pred + s*HW : targ + (s-24)*HW) + r*256;
        float2* out = (float2*)(ws + (s < 24 ? FFT_P + s*66048 : FFT_T + (s-24)*66048)) + r*129;
        float2* a = a4[fid];
        #pragma unroll
        for (int j = 0; j < 4; ++j) {
            int i = l + 64*j;
            a[__brev((unsigned)i) >> 24] = make_float2(src[i], 0.f);
        }
        __syncthreads();
        #pragma unroll
        for (int st = 0; st < 8; ++st) {
            int half = 1 << st, m = half << 1;
            #pragma unroll
            for (int kk = 0; kk < 2; ++kk) {
                int bb = l + 64*kk;
                int j = bb & (half - 1);
                int i0 = ((bb >> st) << (st + 1)) + j;
                int i1 = i0 + half;
                float ang = -6.283185307f * (float)j / (float)m;
                float si, co;
                __sincosf(ang, &si, &co);
                float2 u = a[i0], v = a[i1];
                float2 w = make_float2(v.x*co - v.y*si, v.x*si + v.y*co);
                a[i0] = make_float2(u.x + w.x, u.y + w.y);
                a[i1] = make_float2(u.x - w.x, u.y - w.y);
            }
            __syncthreads();
        }
        out[l] = a[l];
        out[l + 64] = a[l + 64];
        if (l == 0) out[128] = a[128];
    }
}

// ================= MEGA2: fused 11x11 window | fft_col =================
__global__ __launch_bounds__(256) void k_mega2(const float* __restrict__ pred,
                                               const float* __restrict__ targ,
                                               float* __restrict__ ws) {
    __shared__ __align__(16) unsigned char sm[33024];
    int tid = threadIdx.x;
    int bid = blockIdx.x;

    if (bid < B_WIN) {
        // ---- window boost: 4-row strip, separable 11x11 from mask ----
        float (*msk)[256] = (float(*)[256])sm;                // 14 x 256
        float (*hs)[256]  = (float(*)[256])(sm + 14336);      // 14 x 256
        float* sb = (float*)(sm + 28672);
        int b = bid >> 6, strip = bid & 63;
        int y0 = strip * 4;
        int x = tid;
        const float* mbase = ws + MASK_OFF + b*HW;
        #pragma unroll
        for (int r = 0; r < 14; ++r) {
            int yy = y0 - 5 + r;
            msk[r][x] = (yy >= 0 && yy < 256) ? mbase[yy*256 + x] : 0.f;
        }
        __syncthreads();
        #pragma unroll
        for (int r = 0; r < 14; ++r) {
            float hsum = 0.f;
            #pragma unroll
            for (int dx = -5; dx <= 5; ++dx) {
                int xx = x + dx;
                if (xx >= 0 && xx < 256) hsum += msk[r][xx];
            }
            hs[r][x] = hsum;
        }
        __syncthreads();
        float acc_e3 = 0.f, acc_sd = 0.f, acc_m = 0.f;
        #pragma unroll
        for (int j = 0; j < 4; ++j) {
            int ry = y0 + j;
            float vs = 0.f;
            #pragma unroll
            for (int dy = 0; dy < 11; ++dy) vs += hs[j + dy][x];
            float m = vs * (1.f/121.f);
            const float* p = pred + b*3*HW + ry*256 + x;
            const float* t = targ + b*3*HW + ry*256 + x;
            float pr = p[0], pg = p[HW], pb = p[2*HW];
            float tr = t[0], tg = t[HW], tb = t[2*HW];
            float e3 = fabsf(pr-tr) + fabsf(pg-tg) + fabsf(pb-tb);
            float tmx = fmaxf(tr, fmaxf(tg, tb)), tmn = fminf(tr, fminf(tg, tb));
            float tsat = (tmx - tmn + 1e-7f) / (tmx + 1e-7f);
            float pmx = fmaxf(pr, fmaxf(pg, pb)), pmn = fminf(pr, fminf(pg, pb));
            float psat = (pmx - pmn + 1e-7f) / (pmx + 1e-7f);
            acc_e3 += e3 * m;
            acc_sd += fabsf(psat - tsat) * m;
            acc_m  += m;
        }
        float v;
        v = blockSum(acc_e3, sb); if (tid == 0) ws[P_WIN + bid] = v;
        v = blockSum(acc_sd, sb); if (tid == 0) ws[P_WIN + 512 + bid] = v;
        v = blockSum(acc_m,  sb); if (tid == 0) ws[P_WIN + 1024 + bid] = v;
    } else {
        // ---- column FFT: 8 columns x {P,T} per block ----
        float2 (*arr)[257] = (float2(*)[257])sm;              // 16 x 257
        float* sb = (float*)(sm + 32896);
        int cb = bid - B_WIN;                                 // 0..407
        int s = cb / 17, kt = cb - s*17;
        int k0 = kt * 8;
        const float2* srcP = (const float2*)(ws + FFT_P) + s*33024;
        const float2* srcT = (const float2*)(ws + FFT_T) + s*33024;
        int kk = tid & 7, r0 = tid >> 3;
        int col = k0 + kk;
        bool valid = (col <= 128);
        #pragma unroll
        for (int rb = 0; rb < 8; ++rb) {
            int r = r0 + rb*32;
            int br = __brev((unsigned)r) >> 24;
            float2 vp = valid ? srcP[r*129 + col] : make_float2(0.f, 0.f);
            arr[kk][br] = vp;
            float2 vt = valid ? srcT[r*129 + col] : make_float2(0.f, 0.f);
            arr[8 + kk][br] = vt;
        }
        __syncthreads();
        int fid = tid >> 4, w = tid & 15;
        float2* a = arr[fid];
        #pragma unroll
        for (int st = 0; st < 8; ++st) {
            int half = 1 << st, m = half << 1;
            #pragma unroll
            for (int q = 0; q < 8; ++q) {
                int bb = w + (q << 4);
                int j = bb & (half - 1);
                int i0 = ((bb >> st) << (st + 1)) + j;
                int i1 = i0 + half;
                float ang = -6.283185307f * (float)j / (float)m;
                float si, co;
                __sincosf(ang, &si, &co);
                float2 u = a[i0], v = a[i1];
                float2 wv = make_float2(v.x*co - v.y*si, v.x*si + v.y*co);
                a[i0] = make_float2(u.x + wv.x, u.y + wv.y);
                a[i1] = make_float2(u.x - wv.x, u.y - wv.y);
            }
            __syncthreads();
        }
        float d1 = 0.f, d2 = 0.f;
        #pragma unroll
        for (int e = 0; e < 8; ++e) {
            int idx = tid + e*256;
            int k = idx >> 8, r = idx & 255;
            if (k0 + k <= 128) {
                float2 zp = arr[k][r], zt = arr[8 + k][r];
                float mp = sqrtf(zp.x*zp.x + zp.y*zp.y);
                float mt = sqrtf(zt.x*zt.x + zt.y*zt.y);
                float d = fabsf(mt - mp) * (1.f/256.f);
                d1 += d; d2 += d*d;
            }
        }
        float v;
        v = blockSum(d1, sb); if (tid == 0) ws[P_FFT + cb] = v;
        v = blockSum(d2, sb); if (tid == 0) ws[P_FFT + 408 + cb] = v;
    }
}

// ================= K_FINAL =================
__global__ __launch_bounds__(256) void k_final(const float* __restrict__ ws,
                                               float* __restrict__ out) {
    __shared__ float shist[3072];
    __shared__ float red[256];
    __shared__ float sb[8];
    int tid = threadIdx.x;
    // hist pre-reduce: 3072 slice-bins x 8 parts (coalesced)
    for (int q = tid; q < 3072; q += 256) {
        int s = q >> 6, k = q & 63;
        float t = 0.f;
        const float* base = ws + P_HIST + s*8*64 + k;
        #pragma unroll
        for (int p = 0; p < 8; ++p) t += base[p*64];
        shist[q] = t;
    }
    // scalar partial reductions
    float a0=0.f, a1=0.f, a2=0.f;
    for (int i = tid; i < 2048; i += 256) {
        a0 += ws[P_POINT + i];
        a1 += ws[P_POINT + 2048 + i];
        a2 += ws[P_POINT + 4096 + i];
    }
    float w0=0.f, w1=0.f, w2=0.f;
    for (int i = tid; i < 512; i += 256) {
        w0 += ws[P_WIN + i];
        w1 += ws[P_WIN + 512 + i];
        w2 += ws[P_WIN + 1024 + i];
    }
    float m0=0.f, m1=0.f;
    for (int i = tid; i < 384; i += 256) {
        m0 += ws[P_MS + i];
        m1 += ws[P_MS + 384 + i];
    }
    float f0=0.f, f1=0.f;
    for (int i = tid; i < 408; i += 256) {
        f0 += ws[P_FFT + i];
        f1 += ws[P_FFT + 408 + i];
    }
    float sum_e3 = blockSum(a0, sb);
    float sum_L  = blockSum(a1, sb);
    float sum_ab = blockSum(a2, sb);
    float wnum   = blockSum(w0, sb);
    float wsat   = blockSum(w1, sb);
    float wm     = blockSum(w2, sb);
    float S2     = blockSum(m0, sb);
    float S4     = blockSum(m1, sb);
    float d1     = blockSum(f0, sb);
    float d2     = blockSum(f1, sb);
    __syncthreads();
    // curve partial reduce
    float cv = 0.f;
    if (tid < 96) {
        int c = tid >> 5, i = tid & 31;
        float cnt=0.f, ps=0.f, ts=0.f;
        for (int ss = c; ss < 24; ss += 3) {
            for (int p = 0; p < 8; ++p) {
                const float* base = ws + P_CURVE + ((ss<<3) + p)*96 + i*3;
                cnt += base[0]; ps += base[1]; ts += base[2];
            }
        }
        if (cnt > 0.f) cv = fabsf(ps - ts) / cnt;
    }
    red[tid] = cv;
    __syncthreads();
    for (int o = 128; o > 0; o >>= 1) { if (tid < o) red[tid] += red[tid + o]; __syncthreads(); }
    float curve = red[0] / 96.f;
    __syncthreads();
    // histogram EMD
    float hacc = 0.f;
    if (tid < 24) {
        const float* hp = shist + tid*64;
        const float* ht = shist + (24 + tid)*64;
        float sp = 0.f, stt = 0.f;
        for (int k = 0; k < 64; ++k) { sp += hp[k]; stt += ht[k]; }
        float ip = 1.f / (sp + 1e-7f), it = 1.f / (stt + 1e-7f);
        float cp = 0.f, ct = 0.f;
        for (int k = 0; k < 64; ++k) {
            cp += hp[k] * ip;
            ct += ht[k] * it;
            hacc += fabsf(cp - ct);
        }
    }
    red[tid] = hacc;
    __syncthreads();
    for (int o = 128; o > 0; o >>= 1) { if (tid < o) red[tid] += red[tid + o]; __syncthreads(); }
    float hl = red[0] / 1536.f;
    if (tid == 0) {
        float l1  = sum_e3 / (float)NEL;
        float lab = (sum_L / (float)NPX) * 0.01f + 2.f * (sum_ab / (2.f * (float)NPX * 128.f));
        float ms  = (l1 + S2 / 393216.f + S4 / 98304.f) * (1.f/3.f);
        const float M = 792576.f;
        float ff  = (d2 / M) / (d1 / M + 1e-8f);
        float wb  = wnum / (wm*3.f + 1e-7f) + 0.5f * (wsat / (wm + 1e-7f));
        out[0] = l1 + 0.3f*ff + 0.4f*lab + 0.3f*ms + 0.4f*curve + 0.2f*hl + 0.5f*wb;
    }
}

extern "C" void kernel_launch(void* const* d_in, const int* in_sizes, int n_in,
                              void* d_out, int out_size, void* d_ws, size_t ws_size,
                              hipStream_t stream) {
    const float* pred = (const float*)d_in[0];
    const float* targ = (const float*)d_in[1];
    const float* inp  = (const float*)d_in[2];
    float* ws = (float*)d_ws;
    float* out = (float*)d_out;

    k_mega1<<<G_MEGA1, 256, 0, stream>>>(pred, targ, inp, ws);
    k_mega2<<<G_MEGA2, 256, 0, stream>>>(pred, targ, ws);
    k_final<<<1,       256, 0, stream>>>(ws, out);
}